// Round 11
// baseline (181.456 us; speedup 1.0000x reference)
//
#include <hip/hip_runtime.h>
#include <hip/hip_bf16.h>
#include <stdint.h>

typedef __bf16 bf16_t;
typedef __bf16 bf16x8 __attribute__((ext_vector_type(8)));
typedef __bf16 bf16x4 __attribute__((ext_vector_type(4)));
typedef __bf16 bf16x2 __attribute__((ext_vector_type(2)));
typedef float f32x4 __attribute__((ext_vector_type(4)));
typedef float f32x16 __attribute__((ext_vector_type(16)));
typedef uint32_t u32;
typedef uint32_t u32x4 __attribute__((ext_vector_type(4)));

typedef __attribute__((address_space(1))) void as1void;
typedef __attribute__((address_space(3))) void as3void;

#define QSCALE 0.18033688011112042f   // 0.125 * log2(e), folded into Q

// 12 jobs/bh: j0-3 = unsplit qb=j (len 2qb+2); j4..11 = split (qb=4+((j-4)>>1),
// part=(j-4)&1, len qb+1). LPT order by length: 8,8,8,7,7,6,6,6,5,5,4,2.
__constant__ unsigned char kOrder12[12] = {3, 10, 11, 8, 9, 2, 6, 7, 4, 5, 1, 0};

__device__ __forceinline__ void gll16(const void* g, void* l) {
  __builtin_amdgcn_global_load_lds((as1void*)g, (as3void*)l, 16, 0, 0);
}

__device__ __forceinline__ u32 pack2(float a, float b) {
  bf16x2 t = {(bf16_t)a, (bf16_t)b};
  return __builtin_bit_cast(u32, t);
}

// ---------------- prep: W_eff = W + 2.0*B@A (both) + x cast, one kernel ----
__global__ void prep_all(const float* __restrict__ W_attn, const float* __restrict__ B_attn,
                         const float* __restrict__ A_attn, const float* __restrict__ W_proj,
                         const float* __restrict__ B_proj, const float* __restrict__ A_proj,
                         const float4* __restrict__ x,
                         bf16_t* __restrict__ WaE, bf16_t* __restrict__ WpE,
                         bf16x4* __restrict__ Xb) {
  int bid = blockIdx.x;
  if (bid < 16384) {
    int idx = bid * 256 + threadIdx.x;
    const float *W, *Bm, *Am;
    bf16_t* dst;
    if (idx < 3145728) {
      W = W_attn; Bm = B_attn; Am = A_attn; dst = WaE;
    } else {
      idx -= 3145728;
      W = W_proj; Bm = B_proj; Am = A_proj; dst = WpE;
    }
    int o = idx >> 10, c = idx & 1023;
    float acc = W[idx];
#pragma unroll
    for (int r = 0; r < 8; ++r)
      acc += 2.0f * Bm[o * 8 + r] * Am[r * 1024 + c];
    dst[idx] = (bf16_t)acc;
  } else {
    int i = (bid - 16384) * 256 + threadIdx.x;
    float4 v = x[i];
    bf16x4 o = {(bf16_t)v.x, (bf16_t)v.y, (bf16_t)v.z, (bf16_t)v.w};
    Xb[i] = o;
  }
}

// ---------------- GEMM: C[m][n] = sum_k A[m][k] * Bt[n][k] + bias[n] -------
template <bool QKV>
__global__ __launch_bounds__(256, 3) void gemm_bt(
    const bf16_t* __restrict__ A, const bf16_t* __restrict__ Bt,
    const float* __restrict__ bias,
    bf16_t* __restrict__ Qb, bf16_t* __restrict__ Kb, bf16_t* __restrict__ Vb,
    float* __restrict__ Out) {
  __shared__ bf16_t Als[128][64];
  __shared__ bf16_t Bls[128][64];
  const int m0 = blockIdx.x * 128;
  const int n0 = blockIdx.y * 128;
  const int tid = threadIdx.x;
  const int lane = tid & 63;
  const int w = tid >> 6;
  const int wm = w >> 1, wn = w & 1;
  const int lr = lane & 15, g = lane >> 4;
  const int sw = (lane & 7) << 3;
  const int srow = lane >> 3;
  const int soff = ((lane & 7) ^ srow) * 8;

  f32x4 acc[4][4] = {};

  for (int k0 = 0; k0 < 1024; k0 += 64) {
#pragma unroll
    for (int c = 0; c < 4; ++c) {
      int r = w * 32 + c * 8 + srow;
      gll16(A + (size_t)(m0 + r) * 1024 + k0 + soff, &Als[w * 32 + c * 8][0]);
      gll16(Bt + (size_t)(n0 + r) * 1024 + k0 + soff, &Bls[w * 32 + c * 8][0]);
    }
    __syncthreads();
#pragma unroll
    for (int ks = 0; ks < 2; ++ks) {
      bf16x8 af[4], bfv[4];
#pragma unroll
      for (int i = 0; i < 4; ++i)
        af[i] = *(const bf16x8*)&Als[wm * 64 + i * 16 + lr][(ks * 32 + g * 8) ^ sw];
#pragma unroll
      for (int j = 0; j < 4; ++j)
        bfv[j] = *(const bf16x8*)&Bls[wn * 64 + j * 16 + lr][(ks * 32 + g * 8) ^ sw];
#pragma unroll
      for (int i = 0; i < 4; ++i)
#pragma unroll
        for (int j = 0; j < 4; ++j)
          acc[i][j] = __builtin_amdgcn_mfma_f32_16x16x32_bf16(af[i], bfv[j], acc[i][j], 0, 0, 0);
    }
    __syncthreads();
  }

#pragma unroll
  for (int i = 0; i < 4; ++i) {
#pragma unroll
    for (int j = 0; j < 4; ++j) {
#pragma unroll
      for (int e = 0; e < 4; ++e) {
        int m = m0 + wm * 64 + i * 16 + g * 4 + e;
        int n = n0 + wn * 64 + j * 16 + lr;
        float v = acc[i][j][e] + bias[n];
        if (QKV) {
          int b = m >> 11, t = m & 2047;
          int which = n >> 10, hn = n & 1023;
          int h = hn >> 6, d = hn & 63;
          if (which == 0) v *= QSCALE;  // fold softmax scale into Q
          bf16_t* dst = (which == 0) ? Qb : (which == 1) ? Kb : Vb;
          dst[(((size_t)(b * 16 + h)) * 2048 + t) * 64 + d] = (bf16_t)v;
        } else {
          Out[(size_t)m * 1024 + n] = v;
        }
      }
    }
  }
}

// ---------------- flash attention, causal, hd=64, split-K ------------------
// QBLK=256 (8 waves x 32 q-rows), KVBLK=128, 32x32x16 MFMA, P in registers.
// K+Vt double-buffered (64KB, 2 blocks/CU = 16 waves), 1 barrier/tile.
// Diag tiles: kt=2qb (waves 0-3) and kt=2qb+1 (waves 4-7; 0-3 fully masked).
__global__ __launch_bounds__(512, 4) void attn_fwd(
    const bf16_t* __restrict__ Qb, const bf16_t* __restrict__ Kb,
    const bf16_t* __restrict__ Vb, bf16_t* __restrict__ Ob,
    bf16_t* __restrict__ Po, float* __restrict__ Pml) {
  __shared__ bf16_t Kls[2][128][64];   // K tile, chunk ^= row&7
  __shared__ bf16_t Vt[2][64][128];    // V^T [d][k], Gray key ((d^(d>>1))&7)<<3

  // 384 blocks = 8 xcd x 4 bh x 12 slots (longest-first)
  int id = blockIdx.x;
  int xcd = id & 7, r = id >> 3;
  int bh = xcd * 4 + (r & 3);
  int j = kOrder12[r >> 2];
  int qb, kt0, kt1, part;
  if (j < 4) {
    qb = j; kt0 = 0; kt1 = 2 * qb + 2; part = -1;
  } else {
    qb = 4 + ((j - 4) >> 1);
    part = (j - 4) & 1;
    kt0 = part ? (qb + 1) : 0;
    kt1 = part ? (2 * qb + 2) : (qb + 1);
  }
  int b = bh >> 4, h = bh & 15;

  const int tid = threadIdx.x, lane = tid & 63, w = tid >> 6;
  const int q32 = lane & 31;
  const int hi = lane >> 5;
  const int ksw = (q32 & 7) << 3;
  const int vkey = ((q32 ^ (q32 >> 1)) & 7) << 3;  // Gray; db-independent
  const bf16_t* Qp = Qb + (size_t)bh * 2048 * 64;
  const bf16_t* Kp = Kb + (size_t)bh * 2048 * 64;
  const bf16_t* Vp = Vb + (size_t)bh * 2048 * 64;

  const int q0 = qb * 256;
  const int qrow = q0 + w * 32 + q32;

  // V staging: thread handles 8 k-rows x 2 d-cols (u32 loads, 2 b128 writes)
  const int kbase = (tid >> 5) * 8;    // 0..120
  const int dbase = (tid & 31) * 2;    // 0..62
  // K staging (per wave 2 gll16): source pre-swizzled
  const int ksr = lane >> 3;
  const int kso = ((lane & 7) ^ ksr) * 8;

  bf16x8 qf[4];
#pragma unroll
  for (int ds = 0; ds < 4; ++ds)
    qf[ds] = *(const bf16x8*)(Qp + (size_t)qrow * 64 + ds * 16 + hi * 8);

  float m_run = -3e38f, l_run = 0.f;
  f32x16 o_acc[2] = {};

  // ---- prologue: stage tile kt0 into buffer 0 ----
  {
    const int kp = kt0 * 128;
    u32 rowv[8];
#pragma unroll
    for (int rr = 0; rr < 8; ++rr)
      rowv[rr] = *(const u32*)(Vp + (size_t)(kp + kbase + rr) * 64 + dbase);
#pragma unroll
    for (int c = 0; c < 2; ++c) {
      int rb = w * 16 + c * 8;
      gll16(Kp + (size_t)(kp + rb + ksr) * 64 + kso, &Kls[0][rb][0]);
    }
#pragma unroll
    for (int dd = 0; dd < 2; ++dd) {
      u32 sel = dd ? 0x07060302u : 0x05040100u;
      int4 val;
      val.x = __builtin_amdgcn_perm(rowv[1], rowv[0], sel);
      val.y = __builtin_amdgcn_perm(rowv[3], rowv[2], sel);
      val.z = __builtin_amdgcn_perm(rowv[5], rowv[4], sel);
      val.w = __builtin_amdgcn_perm(rowv[7], rowv[6], sel);
      int d = dbase + dd;
      int key = ((d ^ (d >> 1)) & 7) << 3;
      *(int4*)&Vt[0][d][kbase ^ key] = val;
    }
    __syncthreads();
  }

  int cb = 0;
  for (int kt = kt0; kt < kt1; ++kt) {
    const bool haveNext = (kt + 1 < kt1);
    const int dtile = kt - 2 * qb;   // 0 or 1 => diagonal tiles
    int nfa;
    if (dtile < 0) nfa = 4;
    else if (dtile == 0) nfa = (w < 4) ? (w + 1) : 4;
    else nfa = (w < 4) ? 0 : (w - 3);
    const int dfa = (dtile == 0) ? ((w < 4) ? w : -1)
                                 : ((dtile == 1 && w >= 4) ? (w - 4) : -1);
    const int nb = cb ^ 1;

    // ---- issue next tile's loads (async; complete under compute) ----
    u32 rowv[8];
    if (haveNext) {
      const int kn = (kt + 1) * 128;
#pragma unroll
      for (int rr = 0; rr < 8; ++rr)
        rowv[rr] = *(const u32*)(Vp + (size_t)(kn + kbase + rr) * 64 + dbase);
#pragma unroll
      for (int c = 0; c < 2; ++c) {
        int rb = w * 16 + c * 8;
        gll16(Kp + (size_t)(kn + rb + ksr) * 64 + kso, &Kls[nb][rb][0]);
      }
    }

    // ---- QK^T (swapped): S^T[k][q], 32x32 frags; lane owns q-col qrow ----
    f32x16 s[4] = {};
    __builtin_amdgcn_s_setprio(1);
#pragma unroll
    for (int fa = 0; fa < 4; ++fa) {
      if (fa < nfa) {
#pragma unroll
        for (int ds = 0; ds < 4; ++ds) {
          bf16x8 kf = *(const bf16x8*)&Kls[cb][fa * 32 + q32][(ds * 16 + hi * 8) ^ ksw];
          s[fa] = __builtin_amdgcn_mfma_f32_32x32x16_bf16(kf, qf[ds], s[fa], 0, 0, 0);
        }
      }
    }
    __builtin_amdgcn_s_setprio(0);

    // ---- softmax: mask (diag frag only) + lane-local max (+1 shfl) ----
    float mloc = -3e38f;
#pragma unroll
    for (int fa = 0; fa < 4; ++fa) {
      if (fa < nfa) {
        if (fa == dfa) {
#pragma unroll
          for (int rr = 0; rr < 16; ++rr) {
            int km = (rr & 3) + 8 * (rr >> 2) + 4 * hi;
            if (km > q32) s[fa][rr] = -3e38f;
          }
        }
#pragma unroll
        for (int rr = 0; rr < 16; ++rr) mloc = fmaxf(mloc, s[fa][rr]);
      }
    }
    mloc = fmaxf(mloc, __shfl_xor(mloc, 32, 64));
    if (!__all(mloc <= m_run + 8.0f)) {  // defer-max (T13)
      float mnew = fmaxf(m_run, mloc);
      float rs = __builtin_amdgcn_exp2f(m_run - mnew);
      m_run = mnew;
      l_run *= rs;
      o_acc[0] *= rs;
      o_acc[1] *= rs;
    }

    // ---- write next V^T tile ----
    if (haveNext) {
#pragma unroll
      for (int dd = 0; dd < 2; ++dd) {
        u32 sel = dd ? 0x07060302u : 0x05040100u;
        int4 val;
        val.x = __builtin_amdgcn_perm(rowv[1], rowv[0], sel);
        val.y = __builtin_amdgcn_perm(rowv[3], rowv[2], sel);
        val.z = __builtin_amdgcn_perm(rowv[5], rowv[4], sel);
        val.w = __builtin_amdgcn_perm(rowv[7], rowv[6], sel);
        int d = dbase + dd;
        int key = ((d ^ (d >> 1)) & 7) << 3;
        *(int4*)&Vt[nb][d][kbase ^ key] = val;
      }
    }

    // ---- exp + in-register P-frag build (pack + shfl_xor exchange) + PV ----
    float lsum = 0.f;
#pragma unroll
    for (int fa = 0; fa < 4; ++fa) {
      if (fa < nfa) {
        float p[16];
#pragma unroll
        for (int rr = 0; rr < 16; ++rr) {
          p[rr] = __builtin_amdgcn_exp2f(s[fa][rr] - m_run);
          lsum += p[rr];
        }
        u32 x0 = pack2(p[0], p[1]),   x1 = pack2(p[2], p[3]);
        u32 x2 = pack2(p[4], p[5]),   x3 = pack2(p[6], p[7]);
        u32 y0 = pack2(p[8], p[9]),   y1 = pack2(p[10], p[11]);
        u32 y2 = pack2(p[12], p[13]), y3 = pack2(p[14], p[15]);
        u32 z0 = hi ? x0 : x2;
        u32 z1 = hi ? x1 : x3;
        u32 z2 = hi ? y0 : y2;
        u32 z3 = hi ? y1 : y3;
        z0 = (u32)__shfl_xor((int)z0, 32, 64);
        z1 = (u32)__shfl_xor((int)z1, 32, 64);
        z2 = (u32)__shfl_xor((int)z2, 32, 64);
        z3 = (u32)__shfl_xor((int)z3, 32, 64);
        u32x4 pw0 = hi ? (u32x4){z0, z1, x2, x3} : (u32x4){x0, x1, z0, z1};
        u32x4 pw1 = hi ? (u32x4){z2, z3, y2, y3} : (u32x4){y0, y1, z2, z3};
        bf16x8 P0 = __builtin_bit_cast(bf16x8, pw0);
        bf16x8 P1 = __builtin_bit_cast(bf16x8, pw1);
        __builtin_amdgcn_s_setprio(1);
#pragma unroll
        for (int db = 0; db < 2; ++db) {
          int d = db * 32 + q32;
          bf16x8 vf0 = *(const bf16x8*)&Vt[cb][d][(fa * 32 + hi * 8) ^ vkey];
          o_acc[db] = __builtin_amdgcn_mfma_f32_32x32x16_bf16(vf0, P0, o_acc[db], 0, 0, 0);
          bf16x8 vf1 = *(const bf16x8*)&Vt[cb][d][(fa * 32 + 16 + hi * 8) ^ vkey];
          o_acc[db] = __builtin_amdgcn_mfma_f32_32x32x16_bf16(vf1, P1, o_acc[db], 0, 0, 0);
        }
        __builtin_amdgcn_s_setprio(0);
      }
    }
    lsum += __shfl_xor(lsum, 32, 64);
    l_run += lsum;

    __syncthreads();  // next buffers staged; all reads of cb done
    cb = nb;
  }  // kt

  if (part < 0) {
    float inv = 1.0f / l_run;
    bf16_t* obase = Ob + ((size_t)(b * 2048 + qrow)) * 1024 + h * 64;
#pragma unroll
    for (int db = 0; db < 2; ++db) {
#pragma unroll
      for (int rg = 0; rg < 4; ++rg) {
        bf16x4 ov = {(bf16_t)(o_acc[db][rg * 4 + 0] * inv),
                     (bf16_t)(o_acc[db][rg * 4 + 1] * inv),
                     (bf16_t)(o_acc[db][rg * 4 + 2] * inv),
                     (bf16_t)(o_acc[db][rg * 4 + 3] * inv)};
        *(bf16x4*)(obase + db * 32 + rg * 8 + hi * 4) = ov;
      }
    }
  } else {
    // split job: unnormalized partial (bf16) + m,l (f32)
    int sidx = bh * 8 + (qb - 4) * 2 + part;     // 0..255
    int prow = w * 32 + q32;                     // 0..255
    bf16_t* po = Po + (size_t)sidx * 16384 + prow * 64;
#pragma unroll
    for (int db = 0; db < 2; ++db) {
#pragma unroll
      for (int rg = 0; rg < 4; ++rg) {
        bf16x4 ov = {(bf16_t)o_acc[db][rg * 4 + 0], (bf16_t)o_acc[db][rg * 4 + 1],
                     (bf16_t)o_acc[db][rg * 4 + 2], (bf16_t)o_acc[db][rg * 4 + 3]};
        *(bf16x4*)(po + db * 32 + rg * 8 + hi * 4) = ov;
      }
    }
    if (hi == 0) {
      Pml[sidx * 512 + prow * 2] = m_run;
      Pml[sidx * 512 + prow * 2 + 1] = l_run;
    }
  }
}

// ---------------- merge split-K partials into Ob ---------------------------
__global__ __launch_bounds__(256) void attn_merge(
    const bf16_t* __restrict__ Po, const float* __restrict__ Pml,
    bf16_t* __restrict__ Ob) {
  int blk = blockIdx.x;           // 0..127 = bh(32) x qb4(4)
  int bh = blk >> 2, qb4 = blk & 3;
  int qb = 4 + qb4;
  int b = bh >> 4, h = bh & 15;
  int sA = bh * 8 + qb4 * 2, sB = sA + 1;
  int row = threadIdx.x;          // 0..255

  float mA = Pml[sA * 512 + row * 2], lA = Pml[sA * 512 + row * 2 + 1];
  float mB = Pml[sB * 512 + row * 2], lB = Pml[sB * 512 + row * 2 + 1];
  float m = fmaxf(mA, mB);
  float wA = __builtin_amdgcn_exp2f(mA - m);
  float wB = __builtin_amdgcn_exp2f(mB - m);
  float inv = 1.0f / (lA * wA + lB * wB);
  wA *= inv;
  wB *= inv;

  const bf16_t* pa = Po + (size_t)sA * 16384 + row * 64;
  const bf16_t* pb = Po + (size_t)sB * 16384 + row * 64;
  bf16_t* ob = Ob + ((size_t)(b * 2048 + qb * 256 + row)) * 1024 + h * 64;
#pragma unroll
  for (int u = 0; u < 8; ++u) {
    bf16x8 a = *(const bf16x8*)(pa + u * 8);
    bf16x8 c = *(const bf16x8*)(pb + u * 8);
    bf16x8 o;
#pragma unroll
    for (int i = 0; i < 8; ++i)
      o[i] = (bf16_t)((float)a[i] * wA + (float)c[i] * wB);
    *(bf16x8*)(ob + u * 8) = o;
  }
}

// ---------------------------------------------------------------------------
extern "C" void kernel_launch(void* const* d_in, const int* in_sizes, int n_in,
                              void* d_out, int out_size, void* d_ws, size_t ws_size,
                              hipStream_t stream) {
  const float* x      = (const float*)d_in[0];
  const float* W_attn = (const float*)d_in[1];
  const float* b_attn = (const float*)d_in[2];
  const float* A_attn = (const float*)d_in[3];
  const float* B_attn = (const float*)d_in[4];
  const float* W_proj = (const float*)d_in[5];
  const float* b_proj = (const float*)d_in[6];
  const float* A_proj = (const float*)d_in[7];
  const float* B_proj = (const float*)d_in[8];
  float* out = (float*)d_out;

  char* ws = (char*)d_ws;
  bf16_t* WaE = (bf16_t*)(ws);               // 3072*1024*2 (dead after QKV gemm)
  bf16_t* WpE = (bf16_t*)(ws + 6291456);     // 1024*1024*2
  bf16_t* Xb  = (bf16_t*)(ws + 8388608);     // 4096*1024*2 (dead after QKV gemm)
  bf16_t* Qb  = (bf16_t*)(ws + 16777216);    // [B*H][T][64]
  bf16_t* Kb  = (bf16_t*)(ws + 25165824);
  bf16_t* Vb  = (bf16_t*)(ws + 33554432);
  bf16_t* Ob  = (bf16_t*)(ws + 41943040);    // [B*T][C] bf16
  // split-K partials reuse dead regions during attention:
  float*  Pml = (float*)(ws);                // 256*512*4 = 512KB (in WaE)
  bf16_t* Po  = (bf16_t*)(ws + 8388608);     // 256*16384*2 = 8MB (in Xb)

  prep_all<<<20480, 256, 0, stream>>>(W_attn, B_attn, A_attn, W_proj, B_proj, A_proj,
                                      (const float4*)x, WaE, WpE, (bf16x4*)Xb);

  gemm_bt<true><<<dim3(32, 24), 256, 0, stream>>>(Xb, WaE, b_attn, Qb, Kb, Vb, nullptr);
  attn_fwd<<<384, 512, 0, stream>>>(Qb, Kb, Vb, Ob, Po, Pml);
  attn_merge<<<128, 256, 0, stream>>>(Po, Pml, Ob);
  gemm_bt<false><<<dim3(32, 8), 256, 0, stream>>>(Ob, WpE, b_proj, nullptr, nullptr, nullptr, out);
}

// Round 12
// 119.456 us; speedup vs baseline: 1.5190x; 1.5190x over previous
//
#include <hip/hip_runtime.h>
#include <hip/hip_bf16.h>
#include <stdint.h>

typedef __bf16 bf16_t;
typedef __bf16 bf16x8 __attribute__((ext_vector_type(8)));
typedef __bf16 bf16x4 __attribute__((ext_vector_type(4)));
typedef __bf16 bf16x2 __attribute__((ext_vector_type(2)));
typedef float f32x4 __attribute__((ext_vector_type(4)));
typedef float f32x16 __attribute__((ext_vector_type(16)));
typedef uint32_t u32;
typedef uint32_t u32x4 __attribute__((ext_vector_type(4)));

typedef __attribute__((address_space(1))) void as1void;
typedef __attribute__((address_space(3))) void as3void;

#define QSCALE 0.18033688011112042f   // 0.125 * log2(e), folded into Q

// job order: longest first (len8: 7,20,22,23; len7: 6,16,18,19,21; ...)
__constant__ unsigned char kOrder[24] = {7, 20, 22, 23, 6, 16, 18, 19, 21,
                                         5, 12, 14, 15, 17, 4, 8, 10, 11, 13,
                                         3, 9, 2, 1, 0};

__device__ __forceinline__ void gll16(const void* g, void* l) {
  __builtin_amdgcn_global_load_lds((as1void*)g, (as3void*)l, 16, 0, 0);
}

__device__ __forceinline__ u32 pack2(float a, float b) {
  bf16x2 t = {(bf16_t)a, (bf16_t)b};
  return __builtin_bit_cast(u32, t);
}

// ---------------- prep: W_eff = W + 2.0*B@A (both) + x cast, one kernel ----
__global__ void prep_all(const float* __restrict__ W_attn, const float* __restrict__ B_attn,
                         const float* __restrict__ A_attn, const float* __restrict__ W_proj,
                         const float* __restrict__ B_proj, const float* __restrict__ A_proj,
                         const float4* __restrict__ x,
                         bf16_t* __restrict__ WaE, bf16_t* __restrict__ WpE,
                         bf16x4* __restrict__ Xb) {
  int bid = blockIdx.x;
  if (bid < 16384) {
    int idx = bid * 256 + threadIdx.x;
    const float *W, *Bm, *Am;
    bf16_t* dst;
    if (idx < 3145728) {
      W = W_attn; Bm = B_attn; Am = A_attn; dst = WaE;
    } else {
      idx -= 3145728;
      W = W_proj; Bm = B_proj; Am = A_proj; dst = WpE;
    }
    int o = idx >> 10, c = idx & 1023;
    float acc = W[idx];
#pragma unroll
    for (int r = 0; r < 8; ++r)
      acc += 2.0f * Bm[o * 8 + r] * Am[r * 1024 + c];
    dst[idx] = (bf16_t)acc;
  } else {
    int i = (bid - 16384) * 256 + threadIdx.x;
    float4 v = x[i];
    bf16x4 o = {(bf16_t)v.x, (bf16_t)v.y, (bf16_t)v.z, (bf16_t)v.w};
    Xb[i] = o;
  }
}

// ---------------- V transpose: Vb[bh][t][d] -> Vtg[bh][d][t] ---------------
__global__ __launch_bounds__(256) void transpose_v(
    const bf16_t* __restrict__ Vb, bf16_t* __restrict__ Vtg) {
  __shared__ bf16_t Lt[128][72];
  int blk = blockIdx.x;          // 32 bh x 16 t-blocks
  int bh = blk >> 4, tb = blk & 15;
  int t0 = tb * 128;
  int tid = threadIdx.x;
  {
    int t = tid >> 1, dc = (tid & 1) * 32;
    const bf16_t* p = Vb + (size_t)bh * 131072 + (size_t)(t0 + t) * 64 + dc;
#pragma unroll
    for (int u = 0; u < 4; ++u)
      *(bf16x8*)&Lt[t][dc + u * 8] = *(const bf16x8*)(p + u * 8);
  }
  __syncthreads();
  int d = tid & 63, tg = tid >> 6;
  bf16_t* q = Vtg + (size_t)bh * 131072 + (size_t)d * 2048 + t0 + tg * 32;
#pragma unroll
  for (int u = 0; u < 4; ++u) {
    bf16x8 v;
#pragma unroll
    for (int e = 0; e < 8; ++e) v[e] = Lt[tg * 32 + u * 8 + e][d];
    *(bf16x8*)(q + u * 8) = v;
  }
}

// ---------------- GEMM: C[m][n] = sum_k A[m][k] * Bt[n][k] + bias[n] -------
// 128x128 tile, BK=64, 4 waves, gll16 staging. 1D grid, XCD-chunked decode.
template <bool QKV>
__global__ __launch_bounds__(256, 3) void gemm_bt(
    const bf16_t* __restrict__ A, const bf16_t* __restrict__ Bt,
    const float* __restrict__ bias,
    bf16_t* __restrict__ Qb, bf16_t* __restrict__ Kb, bf16_t* __restrict__ Vb,
    float* __restrict__ Out) {
  __shared__ bf16_t Als[128][64];
  __shared__ bf16_t Bls[128][64];
  int mb, nb;
  if (QKV) {
    // 768 blocks: per XCD two (8m x 6n) chunks -> ~3.5MB L2 working set
    int id = blockIdx.x;
    int xcd = id & 7, s = id >> 3;
    int half = s >= 48 ? 1 : 0;
    int within = s - 48 * half;
    int cm = within & 7, cn = within >> 3;
    int chunkIdx = half * 8 + xcd;
    mb = (chunkIdx & 3) * 8 + cm;
    nb = (chunkIdx >> 2) * 6 + cn;
  } else {
    // 256 blocks: per XCD one (8m x 4n) chunk
    int id = blockIdx.x;
    int xcd = id & 7, s = id >> 3;
    mb = (xcd & 3) * 8 + (s & 7);
    nb = (xcd >> 2) * 4 + (s >> 3);
  }
  const int m0 = mb * 128;
  const int n0 = nb * 128;
  const int tid = threadIdx.x;
  const int lane = tid & 63;
  const int w = tid >> 6;
  const int wm = w >> 1, wn = w & 1;
  const int lr = lane & 15, g = lane >> 4;
  const int sw = (lane & 7) << 3;
  const int srow = lane >> 3;
  const int soff = ((lane & 7) ^ srow) * 8;

  f32x4 acc[4][4] = {};

  for (int k0 = 0; k0 < 1024; k0 += 64) {
#pragma unroll
    for (int c = 0; c < 4; ++c) {
      int r = w * 32 + c * 8 + srow;
      gll16(A + (size_t)(m0 + r) * 1024 + k0 + soff, &Als[w * 32 + c * 8][0]);
      gll16(Bt + (size_t)(n0 + r) * 1024 + k0 + soff, &Bls[w * 32 + c * 8][0]);
    }
    __syncthreads();
#pragma unroll
    for (int ks = 0; ks < 2; ++ks) {
      bf16x8 af[4], bfv[4];
#pragma unroll
      for (int i = 0; i < 4; ++i)
        af[i] = *(const bf16x8*)&Als[wm * 64 + i * 16 + lr][(ks * 32 + g * 8) ^ sw];
#pragma unroll
      for (int j = 0; j < 4; ++j)
        bfv[j] = *(const bf16x8*)&Bls[wn * 64 + j * 16 + lr][(ks * 32 + g * 8) ^ sw];
#pragma unroll
      for (int i = 0; i < 4; ++i)
#pragma unroll
        for (int j = 0; j < 4; ++j)
          acc[i][j] = __builtin_amdgcn_mfma_f32_16x16x32_bf16(af[i], bfv[j], acc[i][j], 0, 0, 0);
    }
    __syncthreads();
  }

#pragma unroll
  for (int i = 0; i < 4; ++i) {
#pragma unroll
    for (int j = 0; j < 4; ++j) {
#pragma unroll
      for (int e = 0; e < 4; ++e) {
        int m = m0 + wm * 64 + i * 16 + g * 4 + e;
        int n = n0 + wn * 64 + j * 16 + lr;
        float v = acc[i][j][e] + bias[n];
        if (QKV) {
          int b = m >> 11, t = m & 2047;
          int which = n >> 10, hn = n & 1023;
          int h = hn >> 6, d = hn & 63;
          if (which == 0) v *= QSCALE;
          bf16_t* dst = (which == 0) ? Qb : (which == 1) ? Kb : Vb;
          dst[(((size_t)(b * 16 + h)) * 2048 + t) * 64 + d] = (bf16_t)v;
        } else {
          Out[(size_t)m * 1024 + n] = v;
        }
      }
    }
  }
}

// ---------------- flash attention, causal, hd=64, split-K ------------------
// QBLK=128 (4 waves x 32 q-rows), KVBLK=128, 32x32x16 MFMA, P in registers.
// K+Vt double-buffered (64KB), 1 barrier/tile; BOTH staged via gll16 DMA
// (V from pre-transposed Vtg with pre-swizzled source).
__global__ __launch_bounds__(256, 2) void attn_fwd(
    const bf16_t* __restrict__ Qb, const bf16_t* __restrict__ Kb,
    const bf16_t* __restrict__ Vtg, bf16_t* __restrict__ Ob,
    bf16_t* __restrict__ Po, float* __restrict__ Pml) {
  __shared__ bf16_t Kls[2][128][64];   // K tile, chunk ^= row&7
  __shared__ bf16_t Vt[2][64][128];    // V^T [d][k], chunk key (d&7)^((d>>2)&7)

  // 768 blocks = 8 xcd x 4 bh x 24 slots (longest-first)
  int id = blockIdx.x;
  int xcd = id & 7, r = id >> 3;
  int bh = xcd * 4 + (r & 3);
  int j = kOrder[r >> 2];
  int qb, kt0, kt1, part;
  if (j < 8) {
    qb = j; kt0 = 0; kt1 = qb + 1; part = -1;
  } else {
    qb = 8 + ((j - 8) >> 1);
    part = (j - 8) & 1;
    int kts = qb + 1, nA = (kts + 1) >> 1;
    kt0 = part ? nA : 0;
    kt1 = part ? kts : nA;
  }
  int b = bh >> 4, h = bh & 15;

  const int tid = threadIdx.x, lane = tid & 63, w = tid >> 6;
  const int q32 = lane & 31;
  const int hi = lane >> 5;
  const int ksw = (q32 & 7) << 3;
  const int vkey = ((q32 & 7) ^ (q32 >> 2)) << 3;
  const bf16_t* Qp = Qb + (size_t)bh * 2048 * 64;
  const bf16_t* Kp = Kb + (size_t)bh * 2048 * 64;
  const bf16_t* Vtp = Vtg + (size_t)bh * 131072;   // [64][2048]

  const int q0 = qb * 128;
  const int qrow = q0 + w * 32 + q32;

  // K staging geometry (pre-swizzled source)
  const int ksr = lane >> 3;
  const int kso = ((lane & 7) ^ ksr) * 8;
  // V staging geometry: call cc covers d rows 16w+4cc..+3; per-lane source
  int vdo[4];
#pragma unroll
  for (int cc = 0; cc < 4; ++cc) {
    int d = 16 * w + 4 * cc + (lane >> 4);
    int key = (d & 7) ^ ((d >> 2) & 7);
    vdo[cc] = d * 2048 + (((lane & 15) ^ key) << 3);
  }

  bf16x8 qf[4];
#pragma unroll
  for (int ds = 0; ds < 4; ++ds)
    qf[ds] = *(const bf16x8*)(Qp + (size_t)qrow * 64 + ds * 16 + hi * 8);

  float m_run = -3e38f, l_run = 0.f;
  f32x16 o_acc[2] = {};

  // ---- prologue: stage tile kt0 into buffer 0 (pure DMA) ----
  {
    const int kp = kt0 * 128;
#pragma unroll
    for (int c = 0; c < 4; ++c) {
      int rb = w * 32 + c * 8;
      gll16(Kp + (size_t)(kp + rb + ksr) * 64 + kso, &Kls[0][rb][0]);
    }
#pragma unroll
    for (int cc = 0; cc < 4; ++cc)
      gll16(Vtp + vdo[cc] + kp, &Vt[0][16 * w + 4 * cc][0]);
    __syncthreads();
  }

  int cb = 0;
  for (int kt = kt0; kt < kt1; ++kt) {
    const bool haveNext = (kt + 1 < kt1);
    const bool maskt = (kt == qb);
    const int nfa = maskt ? (w + 1) : 4;
    const int nb = cb ^ 1;

    // ---- issue next tile's DMA (completes under compute) ----
    if (haveNext) {
      const int kn = (kt + 1) * 128;
#pragma unroll
      for (int c = 0; c < 4; ++c) {
        int rb = w * 32 + c * 8;
        gll16(Kp + (size_t)(kn + rb + ksr) * 64 + kso, &Kls[nb][rb][0]);
      }
#pragma unroll
      for (int cc = 0; cc < 4; ++cc)
        gll16(Vtp + vdo[cc] + kn, &Vt[nb][16 * w + 4 * cc][0]);
    }

    // ---- QK^T (swapped): S^T[k][q], 32x32 frags; lane owns q-col qrow ----
    f32x16 s[4] = {};
    __builtin_amdgcn_s_setprio(1);
#pragma unroll
    for (int fa = 0; fa < 4; ++fa) {
      if (fa < nfa) {
#pragma unroll
        for (int ds = 0; ds < 4; ++ds) {
          bf16x8 kf = *(const bf16x8*)&Kls[cb][fa * 32 + q32][(ds * 16 + hi * 8) ^ ksw];
          s[fa] = __builtin_amdgcn_mfma_f32_32x32x16_bf16(kf, qf[ds], s[fa], 0, 0, 0);
        }
      }
    }
    __builtin_amdgcn_s_setprio(0);

    // ---- softmax: mask (diag tile only) + lane-local max (+1 shfl) ----
    float mloc = -3e38f;
#pragma unroll
    for (int fa = 0; fa < 4; ++fa) {
      if (fa < nfa) {
        if (maskt && fa == w) {
#pragma unroll
          for (int rr = 0; rr < 16; ++rr) {
            int km = (rr & 3) + 8 * (rr >> 2) + 4 * hi;
            if (km > q32) s[fa][rr] = -3e38f;
          }
        }
#pragma unroll
        for (int rr = 0; rr < 16; ++rr) mloc = fmaxf(mloc, s[fa][rr]);
      }
    }
    mloc = fmaxf(mloc, __shfl_xor(mloc, 32, 64));
    if (!__all(mloc <= m_run + 8.0f)) {  // defer-max (T13)
      float mnew = fmaxf(m_run, mloc);
      float rs = __builtin_amdgcn_exp2f(m_run - mnew);
      m_run = mnew;
      l_run *= rs;
      o_acc[0] *= rs;
      o_acc[1] *= rs;
    }

    // ---- exp + in-register P-frag build (pack + shfl_xor exchange) + PV ----
    float lsum = 0.f;
#pragma unroll
    for (int fa = 0; fa < 4; ++fa) {
      if (fa < nfa) {
        float p[16];
#pragma unroll
        for (int rr = 0; rr < 16; ++rr) {
          p[rr] = __builtin_amdgcn_exp2f(s[fa][rr] - m_run);
          lsum += p[rr];
        }
        u32 x0 = pack2(p[0], p[1]),   x1 = pack2(p[2], p[3]);
        u32 x2 = pack2(p[4], p[5]),   x3 = pack2(p[6], p[7]);
        u32 y0 = pack2(p[8], p[9]),   y1 = pack2(p[10], p[11]);
        u32 y2 = pack2(p[12], p[13]), y3 = pack2(p[14], p[15]);
        u32 z0 = hi ? x0 : x2;
        u32 z1 = hi ? x1 : x3;
        u32 z2 = hi ? y0 : y2;
        u32 z3 = hi ? y1 : y3;
        z0 = (u32)__shfl_xor((int)z0, 32, 64);
        z1 = (u32)__shfl_xor((int)z1, 32, 64);
        z2 = (u32)__shfl_xor((int)z2, 32, 64);
        z3 = (u32)__shfl_xor((int)z3, 32, 64);
        u32x4 pw0 = hi ? (u32x4){z0, z1, x2, x3} : (u32x4){x0, x1, z0, z1};
        u32x4 pw1 = hi ? (u32x4){z2, z3, y2, y3} : (u32x4){y0, y1, z2, z3};
        bf16x8 P0 = __builtin_bit_cast(bf16x8, pw0);
        bf16x8 P1 = __builtin_bit_cast(bf16x8, pw1);
        __builtin_amdgcn_s_setprio(1);
#pragma unroll
        for (int db = 0; db < 2; ++db) {
          int d = db * 32 + q32;
          bf16x8 vf0 = *(const bf16x8*)&Vt[cb][d][(fa * 32 + hi * 8) ^ vkey];
          o_acc[db] = __builtin_amdgcn_mfma_f32_32x32x16_bf16(vf0, P0, o_acc[db], 0, 0, 0);
          bf16x8 vf1 = *(const bf16x8*)&Vt[cb][d][(fa * 32 + 16 + hi * 8) ^ vkey];
          o_acc[db] = __builtin_amdgcn_mfma_f32_32x32x16_bf16(vf1, P1, o_acc[db], 0, 0, 0);
        }
        __builtin_amdgcn_s_setprio(0);
      }
    }
    lsum += __shfl_xor(lsum, 32, 64);
    l_run += lsum;

    __syncthreads();  // next buffers staged; all reads of cb done
    cb = nb;
  }  // kt

  const int prow = w * 32 + q32;
  if (part < 0) {
    float inv = 1.0f / l_run;
    bf16_t* obase = Ob + ((size_t)(b * 2048 + qrow)) * 1024 + h * 64;
#pragma unroll
    for (int db = 0; db < 2; ++db) {
#pragma unroll
      for (int rg = 0; rg < 4; ++rg) {
        bf16x4 ov = {(bf16_t)(o_acc[db][rg * 4 + 0] * inv),
                     (bf16_t)(o_acc[db][rg * 4 + 1] * inv),
                     (bf16_t)(o_acc[db][rg * 4 + 2] * inv),
                     (bf16_t)(o_acc[db][rg * 4 + 3] * inv)};
        *(bf16x4*)(obase + db * 32 + rg * 8 + hi * 4) = ov;
      }
    }
  } else {
    // split job: part 0 -> unnormalized partial in-place in Ob; part 1 -> Po
    int sidx = bh * 16 + (qb - 8) * 2 + part;
    bf16_t* po = (part == 0)
        ? Ob + ((size_t)(b * 2048 + qrow)) * 1024 + h * 64
        : Po + (size_t)(bh * 8 + (qb - 8)) * 8192 + prow * 64;
    int stride = (part == 0) ? 1 : 1;  // both row-contiguous at 64 cols
    (void)stride;
#pragma unroll
    for (int db = 0; db < 2; ++db) {
#pragma unroll
      for (int rg = 0; rg < 4; ++rg) {
        bf16x4 ov = {(bf16_t)o_acc[db][rg * 4 + 0], (bf16_t)o_acc[db][rg * 4 + 1],
                     (bf16_t)o_acc[db][rg * 4 + 2], (bf16_t)o_acc[db][rg * 4 + 3]};
        *(bf16x4*)(po + db * 32 + rg * 8 + hi * 4) = ov;
      }
    }
    if (hi == 0) {
      Pml[sidx * 256 + prow * 2] = m_run;
      Pml[sidx * 256 + prow * 2 + 1] = l_run;
    }
  }
}

// ---------------- merge split-K partials (Ob-part0 + Po-part1) -------------
__global__ __launch_bounds__(256) void attn_merge(
    const bf16_t* __restrict__ Po, const float* __restrict__ Pml,
    bf16_t* __restrict__ Ob) {
  int blk = blockIdx.x;           // 0..255 = bh(32) x qb8(8)
  int bh = blk >> 3, qb8 = blk & 7;
  int qb = 8 + qb8;
  int b = bh >> 4, h = bh & 15;
  int sA = bh * 16 + qb8 * 2, sB = sA + 1;
  int t = threadIdx.x;
  int row = t >> 1, c0 = (t & 1) * 32;

  float mA = Pml[sA * 256 + row * 2], lA = Pml[sA * 256 + row * 2 + 1];
  float mB = Pml[sB * 256 + row * 2], lB = Pml[sB * 256 + row * 2 + 1];
  float m = fmaxf(mA, mB);
  float wA = __builtin_amdgcn_exp2f(mA - m);
  float wB = __builtin_amdgcn_exp2f(mB - m);
  float inv = 1.0f / (lA * wA + lB * wB);
  wA *= inv;
  wB *= inv;

  bf16_t* ob = Ob + ((size_t)(b * 2048 + qb * 128 + row)) * 1024 + h * 64 + c0;
  const bf16_t* pb = Po + (size_t)(bh * 8 + qb8) * 8192 + row * 64 + c0;
#pragma unroll
  for (int u = 0; u < 4; ++u) {
    bf16x8 a = *(const bf16x8*)(ob + u * 8);
    bf16x8 c = *(const bf16x8*)(pb + u * 8);
    bf16x8 o;
#pragma unroll
    for (int i = 0; i < 8; ++i)
      o[i] = (bf16_t)((float)a[i] * wA + (float)c[i] * wB);
    *(bf16x8*)(ob + u * 8) = o;
  }
}

// ---------------------------------------------------------------------------
extern "C" void kernel_launch(void* const* d_in, const int* in_sizes, int n_in,
                              void* d_out, int out_size, void* d_ws, size_t ws_size,
                              hipStream_t stream) {
  const float* x      = (const float*)d_in[0];
  const float* W_attn = (const float*)d_in[1];
  const float* b_attn = (const float*)d_in[2];
  const float* A_attn = (const float*)d_in[3];
  const float* B_attn = (const float*)d_in[4];
  const float* W_proj = (const float*)d_in[5];
  const float* b_proj = (const float*)d_in[6];
  const float* A_proj = (const float*)d_in[7];
  const float* B_proj = (const float*)d_in[8];
  float* out = (float*)d_out;

  char* ws = (char*)d_ws;
  bf16_t* WaE = (bf16_t*)(ws);               // 6291456 B (dead after QKV gemm)
  bf16_t* WpE = (bf16_t*)(ws + 6291456);     // 2097152 B (live until proj)
  bf16_t* Xb  = (bf16_t*)(ws + 8388608);     // 8388608 B (dead after QKV gemm)
  bf16_t* Qb  = (bf16_t*)(ws + 16777216);    // [B*H][T][64]
  bf16_t* Kb  = (bf16_t*)(ws + 25165824);
  bf16_t* Vb  = (bf16_t*)(ws + 33554432);
  bf16_t* Ob  = (bf16_t*)(ws + 41943040);    // [B*T][C] bf16
  // reuse of dead regions during attention:
  bf16_t* Vtg = (bf16_t*)(ws + 8388608);     // V^T [bh][64][2048] = 8MB (in Xb)
  bf16_t* Po  = (bf16_t*)(ws);               // 256*8192*2 = 4MB (in WaE)
  float*  Pml = (float*)(ws + 4194304);      // 512*256*4 = 512KB (in WaE)

  prep_all<<<20480, 256, 0, stream>>>(W_attn, B_attn, A_attn, W_proj, B_proj, A_proj,
                                      (const float4*)x, WaE, WpE, (bf16x4*)Xb);

  gemm_bt<true><<<768, 256, 0, stream>>>(Xb, WaE, b_attn, Qb, Kb, Vb, nullptr);
  transpose_v<<<512, 256, 0, stream>>>(Vb, Vtg);
  attn_fwd<<<768, 256, 0, stream>>>(Qb, Kb, Vtg, Ob, Po, Pml);
  attn_merge<<<256, 256, 0, stream>>>(Po, Pml, Ob);
  gemm_bt<false><<<256, 256, 0, stream>>>(Ob, WpE, b_proj, nullptr, nullptr, nullptr, out);
}

// Round 13
// 116.333 us; speedup vs baseline: 1.5598x; 1.0269x over previous
//
#include <hip/hip_runtime.h>
#include <hip/hip_bf16.h>
#include <stdint.h>

typedef __bf16 bf16_t;
typedef __bf16 bf16x8 __attribute__((ext_vector_type(8)));
typedef __bf16 bf16x4 __attribute__((ext_vector_type(4)));
typedef __bf16 bf16x2 __attribute__((ext_vector_type(2)));
typedef float f32x4 __attribute__((ext_vector_type(4)));
typedef float f32x16 __attribute__((ext_vector_type(16)));
typedef uint32_t u32;
typedef uint32_t u32x4 __attribute__((ext_vector_type(4)));

typedef __attribute__((address_space(1))) void as1void;
typedef __attribute__((address_space(3))) void as3void;

#define QSCALE 0.18033688011112042f   // 0.125 * log2(e), folded into Q

// 24 jobs/bh in 64-k-tiles. j<8: full qb=j, len=2qb+2. j>=8: split
// qb=8+((j-8)>>1), part=(j-8)&1, len=qb+1. LPT (longest-first) order:
__constant__ unsigned char kOrder[24] = {7, 22, 23, 20, 21, 6, 18, 19, 16, 17,
                                         5, 14, 15, 12, 13, 4, 10, 11, 8, 9,
                                         3, 2, 1, 0};

__device__ __forceinline__ void gll16(const void* g, void* l) {
  __builtin_amdgcn_global_load_lds((as1void*)g, (as3void*)l, 16, 0, 0);
}

__device__ __forceinline__ u32 pack2(float a, float b) {
  bf16x2 t = {(bf16_t)a, (bf16_t)b};
  return __builtin_bit_cast(u32, t);
}

// ---------------- prep: W_eff = W + 2.0*B@A (both) + x cast, one kernel ----
__global__ void prep_all(const float* __restrict__ W_attn, const float* __restrict__ B_attn,
                         const float* __restrict__ A_attn, const float* __restrict__ W_proj,
                         const float* __restrict__ B_proj, const float* __restrict__ A_proj,
                         const float4* __restrict__ x,
                         bf16_t* __restrict__ WaE, bf16_t* __restrict__ WpE,
                         bf16x4* __restrict__ Xb) {
  int bid = blockIdx.x;
  if (bid < 16384) {
    int idx = bid * 256 + threadIdx.x;
    const float *W, *Bm, *Am;
    bf16_t* dst;
    if (idx < 3145728) {
      W = W_attn; Bm = B_attn; Am = A_attn; dst = WaE;
    } else {
      idx -= 3145728;
      W = W_proj; Bm = B_proj; Am = A_proj; dst = WpE;
    }
    int o = idx >> 10, c = idx & 1023;
    float acc = W[idx];
#pragma unroll
    for (int r = 0; r < 8; ++r)
      acc += 2.0f * Bm[o * 8 + r] * Am[r * 1024 + c];
    dst[idx] = (bf16_t)acc;
  } else {
    int i = (bid - 16384) * 256 + threadIdx.x;
    float4 v = x[i];
    bf16x4 o = {(bf16_t)v.x, (bf16_t)v.y, (bf16_t)v.z, (bf16_t)v.w};
    Xb[i] = o;
  }
}

// ---------------- V transpose: Vb[bh][t][d] -> Vtg[bh][d][t] ---------------
__global__ __launch_bounds__(256) void transpose_v(
    const bf16_t* __restrict__ Vb, bf16_t* __restrict__ Vtg) {
  __shared__ bf16_t Lt[128][72];
  int blk = blockIdx.x;          // 32 bh x 16 t-blocks
  int bh = blk >> 4, tb = blk & 15;
  int t0 = tb * 128;
  int tid = threadIdx.x;
  {
    int t = tid >> 1, dc = (tid & 1) * 32;
    const bf16_t* p = Vb + (size_t)bh * 131072 + (size_t)(t0 + t) * 64 + dc;
#pragma unroll
    for (int u = 0; u < 4; ++u)
      *(bf16x8*)&Lt[t][dc + u * 8] = *(const bf16x8*)(p + u * 8);
  }
  __syncthreads();
  int d = tid & 63, tg = tid >> 6;
  bf16_t* q = Vtg + (size_t)bh * 131072 + (size_t)d * 2048 + t0 + tg * 32;
#pragma unroll
  for (int u = 0; u < 4; ++u) {
    bf16x8 v;
#pragma unroll
    for (int e = 0; e < 8; ++e) v[e] = Lt[tg * 32 + u * 8 + e][d];
    *(bf16x8*)(q + u * 8) = v;
  }
}

// ---------------- GEMM: C[m][n] = sum_k A[m][k] * Bt[n][k] + bias[n] -------
// 128x128 tile, BK=64, 4 waves, gll16 staging, plain 2D grid (proven form).
template <bool QKV>
__global__ __launch_bounds__(256, 3) void gemm_bt(
    const bf16_t* __restrict__ A, const bf16_t* __restrict__ Bt,
    const float* __restrict__ bias,
    bf16_t* __restrict__ Qb, bf16_t* __restrict__ Kb, bf16_t* __restrict__ Vb,
    float* __restrict__ Out) {
  __shared__ bf16_t Als[128][64];
  __shared__ bf16_t Bls[128][64];
  const int m0 = blockIdx.x * 128;
  const int n0 = blockIdx.y * 128;
  const int tid = threadIdx.x;
  const int lane = tid & 63;
  const int w = tid >> 6;
  const int wm = w >> 1, wn = w & 1;
  const int lr = lane & 15, g = lane >> 4;
  const int sw = (lane & 7) << 3;
  const int srow = lane >> 3;
  const int soff = ((lane & 7) ^ srow) * 8;

  f32x4 acc[4][4] = {};

  for (int k0 = 0; k0 < 1024; k0 += 64) {
#pragma unroll
    for (int c = 0; c < 4; ++c) {
      int r = w * 32 + c * 8 + srow;
      gll16(A + (size_t)(m0 + r) * 1024 + k0 + soff, &Als[w * 32 + c * 8][0]);
      gll16(Bt + (size_t)(n0 + r) * 1024 + k0 + soff, &Bls[w * 32 + c * 8][0]);
    }
    __syncthreads();
#pragma unroll
    for (int ks = 0; ks < 2; ++ks) {
      bf16x8 af[4], bfv[4];
#pragma unroll
      for (int i = 0; i < 4; ++i)
        af[i] = *(const bf16x8*)&Als[wm * 64 + i * 16 + lr][(ks * 32 + g * 8) ^ sw];
#pragma unroll
      for (int j = 0; j < 4; ++j)
        bfv[j] = *(const bf16x8*)&Bls[wn * 64 + j * 16 + lr][(ks * 32 + g * 8) ^ sw];
#pragma unroll
      for (int i = 0; i < 4; ++i)
#pragma unroll
        for (int j = 0; j < 4; ++j)
          acc[i][j] = __builtin_amdgcn_mfma_f32_16x16x32_bf16(af[i], bfv[j], acc[i][j], 0, 0, 0);
    }
    __syncthreads();
  }

#pragma unroll
  for (int i = 0; i < 4; ++i) {
#pragma unroll
    for (int j = 0; j < 4; ++j) {
#pragma unroll
      for (int e = 0; e < 4; ++e) {
        int m = m0 + wm * 64 + i * 16 + g * 4 + e;
        int n = n0 + wn * 64 + j * 16 + lr;
        float v = acc[i][j][e] + bias[n];
        if (QKV) {
          int b = m >> 11, t = m & 2047;
          int which = n >> 10, hn = n & 1023;
          int h = hn >> 6, d = hn & 63;
          if (which == 0) v *= QSCALE;
          bf16_t* dst = (which == 0) ? Qb : (which == 1) ? Kb : Vb;
          dst[(((size_t)(b * 16 + h)) * 2048 + t) * 64 + d] = (bf16_t)v;
        } else {
          Out[(size_t)m * 1024 + n] = v;
        }
      }
    }
  }
}

// ---------------- flash attention, causal, hd=64, split-K ------------------
// QBLK=128 (4 waves x 32 q-rows), KVBLK=64, 32x32x16 MFMA, P in registers.
// K+Vt double-buffered [64][64] (32KB -> 4 blocks/CU), pure-DMA staging,
// 1 barrier/tile. Diag 64-tiles: rel = kt-2qb in {0,1}, per-wave nfa/dfa.
__global__ __launch_bounds__(256, 4) void attn_fwd(
    const bf16_t* __restrict__ Qb, const bf16_t* __restrict__ Kb,
    const bf16_t* __restrict__ Vtg, bf16_t* __restrict__ Ob,
    bf16_t* __restrict__ Po, float* __restrict__ Pml) {
  __shared__ bf16_t Kls[2][64][64];   // K tile; LDS[r][c*8] = K[r][(c^(r&7))*8]
  __shared__ bf16_t Vt[2][64][64];    // V^T tile; same swizzle on k-chunks

  // 768 blocks = 8 xcd x 4 bh x 24 slots (longest-first)
  int id = blockIdx.x;
  int xcd = id & 7, r = id >> 3;
  int bh = xcd * 4 + (r & 3);
  int j = kOrder[r >> 2];
  int qb, kt0, kt1, part;
  if (j < 8) {
    qb = j; kt0 = 0; kt1 = 2 * qb + 2; part = -1;
  } else {
    qb = 8 + ((j - 8) >> 1);
    part = (j - 8) & 1;
    int nA = qb + 1;
    kt0 = part ? nA : 0;
    kt1 = part ? (2 * qb + 2) : nA;
  }
  int b = bh >> 4, h = bh & 15;

  const int tid = threadIdx.x, lane = tid & 63, w = tid >> 6;
  const int q32 = lane & 31;
  const int hi = lane >> 5;
  const int ksw = (q32 & 7) << 3;     // read key for both K and V^T tiles
  const bf16_t* Qp = Qb + (size_t)bh * 2048 * 64;
  const bf16_t* Kp = Kb + (size_t)bh * 2048 * 64;
  const bf16_t* Vtp = Vtg + (size_t)bh * 131072;   // [64][2048]

  const int q0 = qb * 128;
  const int qrow = q0 + w * 32 + q32;

  // staging geometry (per lane): 1KB call = 8 rows x 64 cols; pre-swizzled src
  const int sr = lane >> 3;                 // row within call
  const int sc = ((lane & 7) ^ sr) * 8;     // source chunk (elements)
  int vdo[2];
#pragma unroll
  for (int c = 0; c < 2; ++c)
    vdo[c] = (w * 16 + c * 8 + sr) * 2048 + sc;

  bf16x8 qf[4];
#pragma unroll
  for (int ds = 0; ds < 4; ++ds)
    qf[ds] = *(const bf16x8*)(Qp + (size_t)qrow * 64 + ds * 16 + hi * 8);

  float m_run = -3e38f, l_run = 0.f;
  f32x16 o_acc[2] = {};

  // ---- prologue: stage tile kt0 into buffer 0 (pure DMA) ----
  {
    const int kp = kt0 * 64;
#pragma unroll
    for (int c = 0; c < 2; ++c) {
      int rb = w * 16 + c * 8;
      gll16(Kp + (size_t)(kp + rb + sr) * 64 + sc, &Kls[0][rb][0]);
      gll16(Vtp + vdo[c] + kp, &Vt[0][rb][0]);
    }
    __syncthreads();
  }

  int cb = 0;
  for (int kt = kt0; kt < kt1; ++kt) {
    const bool haveNext = (kt + 1 < kt1);
    const int nb = cb ^ 1;

    // ---- issue next tile's DMA (completes under compute) ----
    if (haveNext) {
      const int kn = (kt + 1) * 64;
#pragma unroll
      for (int c = 0; c < 2; ++c) {
        int rb = w * 16 + c * 8;
        gll16(Kp + (size_t)(kn + rb + sr) * 64 + sc, &Kls[nb][rb][0]);
        gll16(Vtp + vdo[c] + kn, &Vt[nb][rb][0]);
      }
    }

    // ---- causal decode: rel 0/1 are diagonal 64-tiles ----
    const int rel = kt - 2 * qb;
    int nfa = 2, dfa = -1;
    if (rel == 0) {
      if (w == 0) { nfa = 1; dfa = 0; }
      else if (w == 1) { dfa = 1; }
    } else if (rel == 1) {
      if (w < 2) nfa = 0;
      else if (w == 2) { nfa = 1; dfa = 0; }
      else { dfa = 1; }
    }

    if (nfa > 0) {
      // ---- QK^T (swapped): S^T[k][q], 32x32 frags ----
      f32x16 s[2] = {};
      __builtin_amdgcn_s_setprio(1);
#pragma unroll
      for (int fa = 0; fa < 2; ++fa) {
        if (fa < nfa) {
#pragma unroll
          for (int ds = 0; ds < 4; ++ds) {
            bf16x8 kf = *(const bf16x8*)&Kls[cb][fa * 32 + q32][(ds * 16 + hi * 8) ^ ksw];
            s[fa] = __builtin_amdgcn_mfma_f32_32x32x16_bf16(kf, qf[ds], s[fa], 0, 0, 0);
          }
        }
      }
      __builtin_amdgcn_s_setprio(0);

      // ---- softmax: mask diag frag + lane-local max (+1 shfl) ----
      float mloc = -3e38f;
#pragma unroll
      for (int fa = 0; fa < 2; ++fa) {
        if (fa < nfa) {
          if (fa == dfa) {
#pragma unroll
            for (int rr = 0; rr < 16; ++rr) {
              int km = (rr & 3) + 8 * (rr >> 2) + 4 * hi;
              if (km > q32) s[fa][rr] = -3e38f;
            }
          }
#pragma unroll
          for (int rr = 0; rr < 16; rr += 2)
            mloc = fmaxf(mloc, fmaxf(s[fa][rr], s[fa][rr + 1]));
        }
      }
      mloc = fmaxf(mloc, __shfl_xor(mloc, 32, 64));
      if (!__all(mloc <= m_run + 8.0f)) {  // defer-max (T13)
        float mnew = fmaxf(m_run, mloc);
        float rs = __builtin_amdgcn_exp2f(m_run - mnew);
        m_run = mnew;
        l_run *= rs;
        o_acc[0] *= rs;
        o_acc[1] *= rs;
      }

      // ---- exp + in-register P-frag build + PV ----
      float lsum = 0.f;
#pragma unroll
      for (int fa = 0; fa < 2; ++fa) {
        if (fa < nfa) {
          float p[16];
#pragma unroll
          for (int rr = 0; rr < 16; ++rr) {
            p[rr] = __builtin_amdgcn_exp2f(s[fa][rr] - m_run);
            lsum += p[rr];
          }
          u32 x0 = pack2(p[0], p[1]),   x1 = pack2(p[2], p[3]);
          u32 x2 = pack2(p[4], p[5]),   x3 = pack2(p[6], p[7]);
          u32 y0 = pack2(p[8], p[9]),   y1 = pack2(p[10], p[11]);
          u32 y2 = pack2(p[12], p[13]), y3 = pack2(p[14], p[15]);
          u32 z0 = hi ? x0 : x2;
          u32 z1 = hi ? x1 : x3;
          u32 z2 = hi ? y0 : y2;
          u32 z3 = hi ? y1 : y3;
          z0 = (u32)__shfl_xor((int)z0, 32, 64);
          z1 = (u32)__shfl_xor((int)z1, 32, 64);
          z2 = (u32)__shfl_xor((int)z2, 32, 64);
          z3 = (u32)__shfl_xor((int)z3, 32, 64);
          u32x4 pw0 = hi ? (u32x4){z0, z1, x2, x3} : (u32x4){x0, x1, z0, z1};
          u32x4 pw1 = hi ? (u32x4){z2, z3, y2, y3} : (u32x4){y0, y1, z2, z3};
          bf16x8 P0 = __builtin_bit_cast(bf16x8, pw0);
          bf16x8 P1 = __builtin_bit_cast(bf16x8, pw1);
          __builtin_amdgcn_s_setprio(1);
#pragma unroll
          for (int db = 0; db < 2; ++db) {
            int d = db * 32 + q32;
            bf16x8 vf0 = *(const bf16x8*)&Vt[cb][d][(fa * 32 + hi * 8) ^ ksw];
            o_acc[db] = __builtin_amdgcn_mfma_f32_32x32x16_bf16(vf0, P0, o_acc[db], 0, 0, 0);
            bf16x8 vf1 = *(const bf16x8*)&Vt[cb][d][(fa * 32 + 16 + hi * 8) ^ ksw];
            o_acc[db] = __builtin_amdgcn_mfma_f32_32x32x16_bf16(vf1, P1, o_acc[db], 0, 0, 0);
          }
          __builtin_amdgcn_s_setprio(0);
        }
      }
      lsum += __shfl_xor(lsum, 32, 64);
      l_run += lsum;
    }

    __syncthreads();  // next buffers staged; all reads of cb done
    cb = nb;
  }  // kt

  const int prow = w * 32 + q32;
  if (part < 0) {
    float inv = 1.0f / l_run;
    bf16_t* obase = Ob + ((size_t)(b * 2048 + qrow)) * 1024 + h * 64;
#pragma unroll
    for (int db = 0; db < 2; ++db) {
#pragma unroll
      for (int rg = 0; rg < 4; ++rg) {
        bf16x4 ov = {(bf16_t)(o_acc[db][rg * 4 + 0] * inv),
                     (bf16_t)(o_acc[db][rg * 4 + 1] * inv),
                     (bf16_t)(o_acc[db][rg * 4 + 2] * inv),
                     (bf16_t)(o_acc[db][rg * 4 + 3] * inv)};
        *(bf16x4*)(obase + db * 32 + rg * 8 + hi * 4) = ov;
      }
    }
  } else {
    // split job: part 0 -> unnormalized partial in-place in Ob; part 1 -> Po
    int sidx = bh * 16 + (qb - 8) * 2 + part;
    bf16_t* po = (part == 0)
        ? Ob + ((size_t)(b * 2048 + qrow)) * 1024 + h * 64
        : Po + (size_t)(bh * 8 + (qb - 8)) * 8192 + prow * 64;
#pragma unroll
    for (int db = 0; db < 2; ++db) {
#pragma unroll
      for (int rg = 0; rg < 4; ++rg) {
        bf16x4 ov = {(bf16_t)o_acc[db][rg * 4 + 0], (bf16_t)o_acc[db][rg * 4 + 1],
                     (bf16_t)o_acc[db][rg * 4 + 2], (bf16_t)o_acc[db][rg * 4 + 3]};
        *(bf16x4*)(po + db * 32 + rg * 8 + hi * 4) = ov;
      }
    }
    if (hi == 0) {
      Pml[sidx * 256 + prow * 2] = m_run;
      Pml[sidx * 256 + prow * 2 + 1] = l_run;
    }
  }
}

// ---------------- merge split-K partials (Ob-part0 + Po-part1) -------------
__global__ __launch_bounds__(256) void attn_merge(
    const bf16_t* __restrict__ Po, const float* __restrict__ Pml,
    bf16_t* __restrict__ Ob) {
  int blk = blockIdx.x;           // 0..255 = bh(32) x qb8(8)
  int bh = blk >> 3, qb8 = blk & 7;
  int qb = 8 + qb8;
  int b = bh >> 4, h = bh & 15;
  int sA = bh * 16 + qb8 * 2, sB = sA + 1;
  int t = threadIdx.x;
  int row = t >> 1, c0 = (t & 1) * 32;

  float mA = Pml[sA * 256 + row * 2], lA = Pml[sA * 256 + row * 2 + 1];
  float mB = Pml[sB * 256 + row * 2], lB = Pml[sB * 256 + row * 2 + 1];
  float m = fmaxf(mA, mB);
  float wA = __builtin_amdgcn_exp2f(mA - m);
  float wB = __builtin_amdgcn_exp2f(mB - m);
  float inv = 1.0f / (lA * wA + lB * wB);
  wA *= inv;
  wB *= inv;

  bf16_t* ob = Ob + ((size_t)(b * 2048 + qb * 128 + row)) * 1024 + h * 64 + c0;
  const bf16_t* pb = Po + (size_t)(bh * 8 + qb8) * 8192 + row * 64 + c0;
#pragma unroll
  for (int u = 0; u < 4; ++u) {
    bf16x8 a = *(const bf16x8*)(ob + u * 8);
    bf16x8 c = *(const bf16x8*)(pb + u * 8);
    bf16x8 o;
#pragma unroll
    for (int i = 0; i < 8; ++i)
      o[i] = (bf16_t)((float)a[i] * wA + (float)c[i] * wB);
    *(bf16x8*)(ob + u * 8) = o;
  }
}

// ---------------------------------------------------------------------------
extern "C" void kernel_launch(void* const* d_in, const int* in_sizes, int n_in,
                              void* d_out, int out_size, void* d_ws, size_t ws_size,
                              hipStream_t stream) {
  const float* x      = (const float*)d_in[0];
  const float* W_attn = (const float*)d_in[1];
  const float* b_attn = (const float*)d_in[2];
  const float* A_attn = (const float*)d_in[3];
  const float* B_attn = (const float*)d_in[4];
  const float* W_proj = (const float*)d_in[5];
  const float* b_proj = (const float*)d_in[6];
  const float* A_proj = (const float*)d_in[7];
  const float* B_proj = (const float*)d_in[8];
  float* out = (float*)d_out;

  char* ws = (char*)d_ws;
  bf16_t* WaE = (bf16_t*)(ws);               // dead after QKV gemm
  bf16_t* WpE = (bf16_t*)(ws + 6291456);     // live until proj
  bf16_t* Xb  = (bf16_t*)(ws + 8388608);     // dead after QKV gemm
  bf16_t* Qb  = (bf16_t*)(ws + 16777216);    // [B*H][T][64]
  bf16_t* Kb  = (bf16_t*)(ws + 25165824);
  bf16_t* Vb  = (bf16_t*)(ws + 33554432);
  bf16_t* Ob  = (bf16_t*)(ws + 41943040);    // [B*T][C] bf16
  // reuse of dead regions during attention:
  bf16_t* Vtg = (bf16_t*)(ws + 8388608);     // V^T [bh][64][2048] (in Xb)
  bf16_t* Po  = (bf16_t*)(ws);               // 4MB (in WaE)
  float*  Pml = (float*)(ws + 4194304);      // 512KB (in WaE)

  prep_all<<<20480, 256, 0, stream>>>(W_attn, B_attn, A_attn, W_proj, B_proj, A_proj,
                                      (const float4*)x, WaE, WpE, (bf16x4*)Xb);

  gemm_bt<true><<<dim3(32, 24), 256, 0, stream>>>(Xb, WaE, b_attn, Qb, Kb, Vb, nullptr);
  transpose_v<<<512, 256, 0, stream>>>(Vb, Vtg);
  attn_fwd<<<768, 256, 0, stream>>>(Qb, Kb, Vtg, Ob, Po, Pml);
  attn_merge<<<256, 256, 0, stream>>>(Po, Pml, Ob);
  gemm_bt<false><<<dim3(32, 8), 256, 0, stream>>>(Ob, WpE, b_proj, nullptr, nullptr, nullptr, out);
}

// Round 14
// 115.131 us; speedup vs baseline: 1.5761x; 1.0104x over previous
//
#include <hip/hip_runtime.h>
#include <hip/hip_bf16.h>
#include <stdint.h>

typedef __bf16 bf16_t;
typedef __bf16 bf16x8 __attribute__((ext_vector_type(8)));
typedef __bf16 bf16x4 __attribute__((ext_vector_type(4)));
typedef __bf16 bf16x2 __attribute__((ext_vector_type(2)));
typedef float f32x4 __attribute__((ext_vector_type(4)));
typedef float f32x16 __attribute__((ext_vector_type(16)));
typedef uint32_t u32;
typedef uint32_t u32x4 __attribute__((ext_vector_type(4)));

typedef __attribute__((address_space(1))) void as1void;
typedef __attribute__((address_space(3))) void as3void;

#define QSCALE 0.18033688011112042f   // 0.125 * log2(e), folded into Q

// 24 jobs/bh in 64-k-tiles. j<8: full qb=j, len=2qb+2. j>=8: split
// qb=8+((j-8)>>1), part=(j-8)&1, len=qb+1. LPT (longest-first) order:
__constant__ unsigned char kOrder[24] = {7, 22, 23, 20, 21, 6, 18, 19, 16, 17,
                                         5, 14, 15, 12, 13, 4, 10, 11, 8, 9,
                                         3, 2, 1, 0};

__device__ __forceinline__ void gll16(const void* g, void* l) {
  __builtin_amdgcn_global_load_lds((as1void*)g, (as3void*)l, 16, 0, 0);
}

__device__ __forceinline__ u32 pack2(float a, float b) {
  bf16x2 t = {(bf16_t)a, (bf16_t)b};
  return __builtin_bit_cast(u32, t);
}

// ---------------- prep: W_eff = W + 2.0*B@A (both) + x cast, one kernel ----
__global__ void prep_all(const float* __restrict__ W_attn, const float* __restrict__ B_attn,
                         const float* __restrict__ A_attn, const float* __restrict__ W_proj,
                         const float* __restrict__ B_proj, const float* __restrict__ A_proj,
                         const float4* __restrict__ x,
                         bf16_t* __restrict__ WaE, bf16_t* __restrict__ WpE,
                         bf16x4* __restrict__ Xb) {
  int bid = blockIdx.x;
  if (bid < 16384) {
    int idx = bid * 256 + threadIdx.x;
    const float *W, *Bm, *Am;
    bf16_t* dst;
    if (idx < 3145728) {
      W = W_attn; Bm = B_attn; Am = A_attn; dst = WaE;
    } else {
      idx -= 3145728;
      W = W_proj; Bm = B_proj; Am = A_proj; dst = WpE;
    }
    int o = idx >> 10, c = idx & 1023;
    float acc = W[idx];
#pragma unroll
    for (int r = 0; r < 8; ++r)
      acc += 2.0f * Bm[o * 8 + r] * Am[r * 1024 + c];
    dst[idx] = (bf16_t)acc;
  } else {
    int i = (bid - 16384) * 256 + threadIdx.x;
    float4 v = x[i];
    bf16x4 o = {(bf16_t)v.x, (bf16_t)v.y, (bf16_t)v.z, (bf16_t)v.w};
    Xb[i] = o;
  }
}

// ---------------- V transpose: Vb[bh][t][d] -> Vtg[bh][d][t] ---------------
__global__ __launch_bounds__(256) void transpose_v(
    const bf16_t* __restrict__ Vb, bf16_t* __restrict__ Vtg) {
  __shared__ bf16_t Lt[128][72];
  int blk = blockIdx.x;          // 32 bh x 16 t-blocks
  int bh = blk >> 4, tb = blk & 15;
  int t0 = tb * 128;
  int tid = threadIdx.x;
  {
    int t = tid >> 1, dc = (tid & 1) * 32;
    const bf16_t* p = Vb + (size_t)bh * 131072 + (size_t)(t0 + t) * 64 + dc;
#pragma unroll
    for (int u = 0; u < 4; ++u)
      *(bf16x8*)&Lt[t][dc + u * 8] = *(const bf16x8*)(p + u * 8);
  }
  __syncthreads();
  int d = tid & 63, tg = tid >> 6;
  bf16_t* q = Vtg + (size_t)bh * 131072 + (size_t)d * 2048 + t0 + tg * 32;
#pragma unroll
  for (int u = 0; u < 4; ++u) {
    bf16x8 v;
#pragma unroll
    for (int e = 0; e < 8; ++e) v[e] = Lt[tg * 32 + u * 8 + e][d];
    *(bf16x8*)(q + u * 8) = v;
  }
}

// ---------------- GEMM: C[m][n] = sum_k A[m][k] * Bt[n][k] + bias[n] -------
// 128x128 tile, BK=64, 4 waves, gll16 staging, plain 2D grid (proven form).
template <bool QKV>
__global__ __launch_bounds__(256, 3) void gemm_bt(
    const bf16_t* __restrict__ A, const bf16_t* __restrict__ Bt,
    const float* __restrict__ bias,
    bf16_t* __restrict__ Qb, bf16_t* __restrict__ Kb, bf16_t* __restrict__ Vb,
    float* __restrict__ Out) {
  __shared__ bf16_t Als[128][64];
  __shared__ bf16_t Bls[128][64];
  const int m0 = blockIdx.x * 128;
  const int n0 = blockIdx.y * 128;
  const int tid = threadIdx.x;
  const int lane = tid & 63;
  const int w = tid >> 6;
  const int wm = w >> 1, wn = w & 1;
  const int lr = lane & 15, g = lane >> 4;
  const int sw = (lane & 7) << 3;
  const int srow = lane >> 3;
  const int soff = ((lane & 7) ^ srow) * 8;

  f32x4 acc[4][4] = {};

  for (int k0 = 0; k0 < 1024; k0 += 64) {
#pragma unroll
    for (int c = 0; c < 4; ++c) {
      int r = w * 32 + c * 8 + srow;
      gll16(A + (size_t)(m0 + r) * 1024 + k0 + soff, &Als[w * 32 + c * 8][0]);
      gll16(Bt + (size_t)(n0 + r) * 1024 + k0 + soff, &Bls[w * 32 + c * 8][0]);
    }
    __syncthreads();
#pragma unroll
    for (int ks = 0; ks < 2; ++ks) {
      bf16x8 af[4], bfv[4];
#pragma unroll
      for (int i = 0; i < 4; ++i)
        af[i] = *(const bf16x8*)&Als[wm * 64 + i * 16 + lr][(ks * 32 + g * 8) ^ sw];
#pragma unroll
      for (int j = 0; j < 4; ++j)
        bfv[j] = *(const bf16x8*)&Bls[wn * 64 + j * 16 + lr][(ks * 32 + g * 8) ^ sw];
#pragma unroll
      for (int i = 0; i < 4; ++i)
#pragma unroll
        for (int j = 0; j < 4; ++j)
          acc[i][j] = __builtin_amdgcn_mfma_f32_16x16x32_bf16(af[i], bfv[j], acc[i][j], 0, 0, 0);
    }
    __syncthreads();
  }

#pragma unroll
  for (int i = 0; i < 4; ++i) {
#pragma unroll
    for (int j = 0; j < 4; ++j) {
#pragma unroll
      for (int e = 0; e < 4; ++e) {
        int m = m0 + wm * 64 + i * 16 + g * 4 + e;
        int n = n0 + wn * 64 + j * 16 + lr;
        float v = acc[i][j][e] + bias[n];
        if (QKV) {
          int b = m >> 11, t = m & 2047;
          int which = n >> 10, hn = n & 1023;
          int h = hn >> 6, d = hn & 63;
          if (which == 0) v *= QSCALE;
          bf16_t* dst = (which == 0) ? Qb : (which == 1) ? Kb : Vb;
          dst[(((size_t)(b * 16 + h)) * 2048 + t) * 64 + d] = (bf16_t)v;
        } else {
          Out[(size_t)m * 1024 + n] = v;
        }
      }
    }
  }
}

// ---------------- flash attention, causal, hd=64, split-K ------------------
// QBLK=128 (4 waves x 32 q-rows), KVBLK=64, 32x32x16 MFMA, P in registers.
// K+Vt TRIPLE-buffered [64][64] (48KB -> 3 blocks/CU), pure-DMA staging,
// prefetch distance 2, counted vmcnt(4) + raw s_barrier (T3/T4): next-next
// tile's loads stay in flight across the barrier; never drain to 0 mid-loop.
__global__ __launch_bounds__(256, 3) void attn_fwd(
    const bf16_t* __restrict__ Qb, const bf16_t* __restrict__ Kb,
    const bf16_t* __restrict__ Vtg, bf16_t* __restrict__ Ob,
    bf16_t* __restrict__ Po, float* __restrict__ Pml) {
  __shared__ bf16_t Kls[3][64][64];   // K tile; LDS[r][c*8] = K[r][(c^(r&7))*8]
  __shared__ bf16_t Vt[3][64][64];    // V^T tile; same swizzle on k-chunks

  // 768 blocks = 8 xcd x 4 bh x 24 slots (longest-first)
  int id = blockIdx.x;
  int xcd = id & 7, r = id >> 3;
  int bh = xcd * 4 + (r & 3);
  int j = kOrder[r >> 2];
  int qb, kt0, kt1, part;
  if (j < 8) {
    qb = j; kt0 = 0; kt1 = 2 * qb + 2; part = -1;
  } else {
    qb = 8 + ((j - 8) >> 1);
    part = (j - 8) & 1;
    int nA = qb + 1;
    kt0 = part ? nA : 0;
    kt1 = part ? (2 * qb + 2) : nA;
  }
  int b = bh >> 4, h = bh & 15;

  const int tid = threadIdx.x, lane = tid & 63, w = tid >> 6;
  const int q32 = lane & 31;
  const int hi = lane >> 5;
  const int ksw = (q32 & 7) << 3;     // read key for both K and V^T tiles
  const bf16_t* Qp = Qb + (size_t)bh * 2048 * 64;
  const bf16_t* Kp = Kb + (size_t)bh * 2048 * 64;
  const bf16_t* Vtp = Vtg + (size_t)bh * 131072;   // [64][2048]

  const int q0 = qb * 128;
  const int qrow = q0 + w * 32 + q32;

  // staging geometry (per lane): 1KB call = 8 rows x 64 cols; pre-swizzled src
  const int sr = lane >> 3;                 // row within call
  const int sc = ((lane & 7) ^ sr) * 8;     // source chunk (elements)
  int vdo[2];
#pragma unroll
  for (int c = 0; c < 2; ++c)
    vdo[c] = (w * 16 + c * 8 + sr) * 2048 + sc;

  bf16x8 qf[4];
#pragma unroll
  for (int ds = 0; ds < 4; ++ds)
    qf[ds] = *(const bf16x8*)(Qp + (size_t)qrow * 64 + ds * 16 + hi * 8);

  float m_run = -3e38f, l_run = 0.f;
  f32x16 o_acc[2] = {};

  // ---- prologue: stage tiles kt0 -> buf0, kt0+1 -> buf1 (pure DMA) ----
  {
    const int kp = kt0 * 64;
#pragma unroll
    for (int c = 0; c < 2; ++c) {
      int rb = w * 16 + c * 8;
      gll16(Kp + (size_t)(kp + rb + sr) * 64 + sc, &Kls[0][rb][0]);
      gll16(Vtp + vdo[c] + kp, &Vt[0][rb][0]);
    }
    const int kp1 = kp + 64;   // kt0+1 < kt1 always (min job len 2)
#pragma unroll
    for (int c = 0; c < 2; ++c) {
      int rb = w * 16 + c * 8;
      gll16(Kp + (size_t)(kp1 + rb + sr) * 64 + sc, &Kls[1][rb][0]);
      gll16(Vtp + vdo[c] + kp1, &Vt[1][rb][0]);
    }
    asm volatile("s_waitcnt vmcnt(4)" ::: "memory");  // buf0 (+Q) complete
    __builtin_amdgcn_s_barrier();
  }

  int cb = 0;
  for (int kt = kt0; kt < kt1; ++kt) {
    const bool pf2 = (kt + 2 < kt1);
    const int pf = (cb >= 1) ? cb - 1 : 2;   // (cb+2)%3

    // ---- issue tile kt+2's DMA (stays in flight across the barrier) ----
    if (pf2) {
      const int kn = (kt + 2) * 64;
#pragma unroll
      for (int c = 0; c < 2; ++c) {
        int rb = w * 16 + c * 8;
        gll16(Kp + (size_t)(kn + rb + sr) * 64 + sc, &Kls[pf][rb][0]);
        gll16(Vtp + vdo[c] + kn, &Vt[pf][rb][0]);
      }
    }

    // ---- causal decode: rel 0/1 are diagonal 64-tiles ----
    const int rel = kt - 2 * qb;
    int nfa = 2, dfa = -1;
    if (rel == 0) {
      if (w == 0) { nfa = 1; dfa = 0; }
      else if (w == 1) { dfa = 1; }
    } else if (rel == 1) {
      if (w < 2) nfa = 0;
      else if (w == 2) { nfa = 1; dfa = 0; }
      else { dfa = 1; }
    }

    if (nfa > 0) {
      // ---- QK^T (swapped): S^T[k][q], 32x32 frags ----
      f32x16 s[2] = {};
      __builtin_amdgcn_s_setprio(1);
#pragma unroll
      for (int fa = 0; fa < 2; ++fa) {
        if (fa < nfa) {
#pragma unroll
          for (int ds = 0; ds < 4; ++ds) {
            bf16x8 kf = *(const bf16x8*)&Kls[cb][fa * 32 + q32][(ds * 16 + hi * 8) ^ ksw];
            s[fa] = __builtin_amdgcn_mfma_f32_32x32x16_bf16(kf, qf[ds], s[fa], 0, 0, 0);
          }
        }
      }
      __builtin_amdgcn_s_setprio(0);

      // ---- softmax: mask diag frag + lane-local max (+1 shfl) ----
      float mloc = -3e38f;
#pragma unroll
      for (int fa = 0; fa < 2; ++fa) {
        if (fa < nfa) {
          if (fa == dfa) {
#pragma unroll
            for (int rr = 0; rr < 16; ++rr) {
              int km = (rr & 3) + 8 * (rr >> 2) + 4 * hi;
              if (km > q32) s[fa][rr] = -3e38f;
            }
          }
#pragma unroll
          for (int rr = 0; rr < 16; rr += 2)
            mloc = fmaxf(mloc, fmaxf(s[fa][rr], s[fa][rr + 1]));
        }
      }
      mloc = fmaxf(mloc, __shfl_xor(mloc, 32, 64));
      if (!__all(mloc <= m_run + 8.0f)) {  // defer-max (T13)
        float mnew = fmaxf(m_run, mloc);
        float rs = __builtin_amdgcn_exp2f(m_run - mnew);
        m_run = mnew;
        l_run *= rs;
        o_acc[0] *= rs;
        o_acc[1] *= rs;
      }

      // ---- exp + in-register P-frag build + PV ----
      float lsum = 0.f;
#pragma unroll
      for (int fa = 0; fa < 2; ++fa) {
        if (fa < nfa) {
          float p[16];
#pragma unroll
          for (int rr = 0; rr < 16; ++rr) {
            p[rr] = __builtin_amdgcn_exp2f(s[fa][rr] - m_run);
            lsum += p[rr];
          }
          u32 x0 = pack2(p[0], p[1]),   x1 = pack2(p[2], p[3]);
          u32 x2 = pack2(p[4], p[5]),   x3 = pack2(p[6], p[7]);
          u32 y0 = pack2(p[8], p[9]),   y1 = pack2(p[10], p[11]);
          u32 y2 = pack2(p[12], p[13]), y3 = pack2(p[14], p[15]);
          u32 z0 = hi ? x0 : x2;
          u32 z1 = hi ? x1 : x3;
          u32 z2 = hi ? y0 : y2;
          u32 z3 = hi ? y1 : y3;
          z0 = (u32)__shfl_xor((int)z0, 32, 64);
          z1 = (u32)__shfl_xor((int)z1, 32, 64);
          z2 = (u32)__shfl_xor((int)z2, 32, 64);
          z3 = (u32)__shfl_xor((int)z3, 32, 64);
          u32x4 pw0 = hi ? (u32x4){z0, z1, x2, x3} : (u32x4){x0, x1, z0, z1};
          u32x4 pw1 = hi ? (u32x4){z2, z3, y2, y3} : (u32x4){y0, y1, z2, z3};
          bf16x8 P0 = __builtin_bit_cast(bf16x8, pw0);
          bf16x8 P1 = __builtin_bit_cast(bf16x8, pw1);
          __builtin_amdgcn_s_setprio(1);
#pragma unroll
          for (int db = 0; db < 2; ++db) {
            int d = db * 32 + q32;
            bf16x8 vf0 = *(const bf16x8*)&Vt[cb][d][(fa * 32 + hi * 8) ^ ksw];
            o_acc[db] = __builtin_amdgcn_mfma_f32_32x32x16_bf16(vf0, P0, o_acc[db], 0, 0, 0);
            bf16x8 vf1 = *(const bf16x8*)&Vt[cb][d][(fa * 32 + 16 + hi * 8) ^ ksw];
            o_acc[db] = __builtin_amdgcn_mfma_f32_32x32x16_bf16(vf1, P1, o_acc[db], 0, 0, 0);
          }
          __builtin_amdgcn_s_setprio(0);
        }
      }
      lsum += __shfl_xor(lsum, 32, 64);
      l_run += lsum;
    }

    // ---- counted-vmcnt barrier: kt+1's loads done; kt+2's stay in flight ----
    if (pf2) {
      asm volatile("s_waitcnt vmcnt(4)" ::: "memory");
    } else {
      asm volatile("s_waitcnt vmcnt(0)" ::: "memory");
    }
    __builtin_amdgcn_s_barrier();
    cb = (cb == 2) ? 0 : cb + 1;
  }  // kt

  const int prow = w * 32 + q32;
  if (part < 0) {
    float inv = 1.0f / l_run;
    bf16_t* obase = Ob + ((size_t)(b * 2048 + qrow)) * 1024 + h * 64;
#pragma unroll
    for (int db = 0; db < 2; ++db) {
#pragma unroll
      for (int rg = 0; rg < 4; ++rg) {
        bf16x4 ov = {(bf16_t)(o_acc[db][rg * 4 + 0] * inv),
                     (bf16_t)(o_acc[db][rg * 4 + 1] * inv),
                     (bf16_t)(o_acc[db][rg * 4 + 2] * inv),
                     (bf16_t)(o_acc[db][rg * 4 + 3] * inv)};
        *(bf16x4*)(obase + db * 32 + rg * 8 + hi * 4) = ov;
      }
    }
  } else {
    // split job: part 0 -> unnormalized partial in-place in Ob; part 1 -> Po
    int sidx = bh * 16 + (qb - 8) * 2 + part;
    bf16_t* po = (part == 0)
        ? Ob + ((size_t)(b * 2048 + qrow)) * 1024 + h * 64
        : Po + (size_t)(bh * 8 + (qb - 8)) * 8192 + prow * 64;
#pragma unroll
    for (int db = 0; db < 2; ++db) {
#pragma unroll
      for (int rg = 0; rg < 4; ++rg) {
        bf16x4 ov = {(bf16_t)o_acc[db][rg * 4 + 0], (bf16_t)o_acc[db][rg * 4 + 1],
                     (bf16_t)o_acc[db][rg * 4 + 2], (bf16_t)o_acc[db][rg * 4 + 3]};
        *(bf16x4*)(po + db * 32 + rg * 8 + hi * 4) = ov;
      }
    }
    if (hi == 0) {
      Pml[sidx * 256 + prow * 2] = m_run;
      Pml[sidx * 256 + prow * 2 + 1] = l_run;
    }
  }
}

// ---------------- merge split-K partials (Ob-part0 + Po-part1) -------------
__global__ __launch_bounds__(256) void attn_merge(
    const bf16_t* __restrict__ Po, const float* __restrict__ Pml,
    bf16_t* __restrict__ Ob) {
  int blk = blockIdx.x;           // 0..255 = bh(32) x qb8(8)
  int bh = blk >> 3, qb8 = blk & 7;
  int qb = 8 + qb8;
  int b = bh >> 4, h = bh & 15;
  int sA = bh * 16 + qb8 * 2, sB = sA + 1;
  int t = threadIdx.x;
  int row = t >> 1, c0 = (t & 1) * 32;

  float mA = Pml[sA * 256 + row * 2], lA = Pml[sA * 256 + row * 2 + 1];
  float mB = Pml[sB * 256 + row * 2], lB = Pml[sB * 256 + row * 2 + 1];
  float m = fmaxf(mA, mB);
  float wA = __builtin_amdgcn_exp2f(mA - m);
  float wB = __builtin_amdgcn_exp2f(mB - m);
  float inv = 1.0f / (lA * wA + lB * wB);
  wA *= inv;
  wB *= inv;

  bf16_t* ob = Ob + ((size_t)(b * 2048 + qb * 128 + row)) * 1024 + h * 64 + c0;
  const bf16_t* pb = Po + (size_t)(bh * 8 + qb8) * 8192 + row * 64 + c0;
#pragma unroll
  for (int u = 0; u < 4; ++u) {
    bf16x8 a = *(const bf16x8*)(ob + u * 8);
    bf16x8 c = *(const bf16x8*)(pb + u * 8);
    bf16x8 o;
#pragma unroll
    for (int i = 0; i < 8; ++i)
      o[i] = (bf16_t)((float)a[i] * wA + (float)c[i] * wB);
    *(bf16x8*)(ob + u * 8) = o;
  }
}

// ---------------------------------------------------------------------------
extern "C" void kernel_launch(void* const* d_in, const int* in_sizes, int n_in,
                              void* d_out, int out_size, void* d_ws, size_t ws_size,
                              hipStream_t stream) {
  const float* x      = (const float*)d_in[0];
  const float* W_attn = (const float*)d_in[1];
  const float* b_attn = (const float*)d_in[2];
  const float* A_attn = (const float*)d_in[3];
  const float* B_attn = (const float*)d_in[4];
  const float* W_proj = (const float*)d_in[5];
  const float* b_proj = (const float*)d_in[6];
  const float* A_proj = (const float*)d_in[7];
  const float* B_proj = (const float*)d_in[8];
  float* out = (float*)d_out;

  char* ws = (char*)d_ws;
  bf16_t* WaE = (bf16_t*)(ws);               // dead after QKV gemm
  bf16_t* WpE = (bf16_t*)(ws + 6291456);     // live until proj
  bf16_t* Xb  = (bf16_t*)(ws + 8388608);     // dead after QKV gemm
  bf16_t* Qb  = (bf16_t*)(ws + 16777216);    // [B*H][T][64]
  bf16_t* Kb  = (bf16_t*)(ws + 25165824);
  bf16_t* Vb  = (bf16_t*)(ws + 33554432);
  bf16_t* Ob  = (bf16_t*)(ws + 41943040);    // [B*T][C] bf16
  // reuse of dead regions during attention:
  bf16_t* Vtg = (bf16_t*)(ws + 8388608);     // V^T [bh][64][2048] (in Xb)
  bf16_t* Po  = (bf16_t*)(ws);               // 4MB (in WaE)
  float*  Pml = (float*)(ws + 4194304);      // 512KB (in WaE)

  prep_all<<<20480, 256, 0, stream>>>(W_attn, B_attn, A_attn, W_proj, B_proj, A_proj,
                                      (const float4*)x, WaE, WpE, (bf16x4*)Xb);

  gemm_bt<true><<<dim3(32, 24), 256, 0, stream>>>(Xb, WaE, b_attn, Qb, Kb, Vb, nullptr);
  transpose_v<<<512, 256, 0, stream>>>(Vb, Vtg);
  attn_fwd<<<768, 256, 0, stream>>>(Qb, Kb, Vtg, Ob, Po, Pml);
  attn_merge<<<256, 256, 0, stream>>>(Po, Pml, Ob);
  gemm_bt<false><<<dim3(32, 8), 256, 0, stream>>>(Ob, WpE, b_proj, nullptr, nullptr, nullptr, out);
}

// Round 15
// 114.182 us; speedup vs baseline: 1.5892x; 1.0083x over previous
//
#include <hip/hip_runtime.h>
#include <hip/hip_bf16.h>
#include <stdint.h>

typedef __bf16 bf16_t;
typedef __bf16 bf16x8 __attribute__((ext_vector_type(8)));
typedef __bf16 bf16x4 __attribute__((ext_vector_type(4)));
typedef __bf16 bf16x2 __attribute__((ext_vector_type(2)));
typedef float f32x4 __attribute__((ext_vector_type(4)));
typedef float f32x16 __attribute__((ext_vector_type(16)));
typedef uint32_t u32;
typedef uint32_t u32x4 __attribute__((ext_vector_type(4)));

typedef __attribute__((address_space(1))) void as1void;
typedef __attribute__((address_space(3))) void as3void;

#define QSCALE 0.18033688011112042f   // 0.125 * log2(e), folded into Q

// 24 jobs/bh in 64-k-tiles. j<8: full qb=j, len=2qb+2. j>=8: split
// qb=8+((j-8)>>1), part=(j-8)&1, len=qb+1. LPT (longest-first) order:
__constant__ unsigned char kOrder[24] = {7, 22, 23, 20, 21, 6, 18, 19, 16, 17,
                                         5, 14, 15, 12, 13, 4, 10, 11, 8, 9,
                                         3, 2, 1, 0};

__device__ __forceinline__ void gll16(const void* g, void* l) {
  __builtin_amdgcn_global_load_lds((as1void*)g, (as3void*)l, 16, 0, 0);
}

__device__ __forceinline__ u32 pack2(float a, float b) {
  bf16x2 t = {(bf16_t)a, (bf16_t)b};
  return __builtin_bit_cast(u32, t);
}

// ---------------- prep: W_eff = W + 2.0*B@A (both) + x cast, one kernel ----
__global__ void prep_all(const float* __restrict__ W_attn, const float* __restrict__ B_attn,
                         const float* __restrict__ A_attn, const float* __restrict__ W_proj,
                         const float* __restrict__ B_proj, const float* __restrict__ A_proj,
                         const float4* __restrict__ x,
                         bf16_t* __restrict__ WaE, bf16_t* __restrict__ WpE,
                         bf16x4* __restrict__ Xb) {
  int bid = blockIdx.x;
  if (bid < 16384) {
    int idx = bid * 256 + threadIdx.x;
    const float *W, *Bm, *Am;
    bf16_t* dst;
    if (idx < 3145728) {
      W = W_attn; Bm = B_attn; Am = A_attn; dst = WaE;
    } else {
      idx -= 3145728;
      W = W_proj; Bm = B_proj; Am = A_proj; dst = WpE;
    }
    int o = idx >> 10, c = idx & 1023;
    float acc = W[idx];
#pragma unroll
    for (int r = 0; r < 8; ++r)
      acc += 2.0f * Bm[o * 8 + r] * Am[r * 1024 + c];
    dst[idx] = (bf16_t)acc;
  } else {
    int i = (bid - 16384) * 256 + threadIdx.x;
    float4 v = x[i];
    bf16x4 o = {(bf16_t)v.x, (bf16_t)v.y, (bf16_t)v.z, (bf16_t)v.w};
    Xb[i] = o;
  }
}

// ---------------- V transpose: Vb[bh][t][d] -> Vtg[bh][d][t] ---------------
__global__ __launch_bounds__(256) void transpose_v(
    const bf16_t* __restrict__ Vb, bf16_t* __restrict__ Vtg) {
  __shared__ bf16_t Lt[128][72];
  int blk = blockIdx.x;          // 32 bh x 16 t-blocks
  int bh = blk >> 4, tb = blk & 15;
  int t0 = tb * 128;
  int tid = threadIdx.x;
  {
    int t = tid >> 1, dc = (tid & 1) * 32;
    const bf16_t* p = Vb + (size_t)bh * 131072 + (size_t)(t0 + t) * 64 + dc;
#pragma unroll
    for (int u = 0; u < 4; ++u)
      *(bf16x8*)&Lt[t][dc + u * 8] = *(const bf16x8*)(p + u * 8);
  }
  __syncthreads();
  int d = tid & 63, tg = tid >> 6;
  bf16_t* q = Vtg + (size_t)bh * 131072 + (size_t)d * 2048 + t0 + tg * 32;
#pragma unroll
  for (int u = 0; u < 4; ++u) {
    bf16x8 v;
#pragma unroll
    for (int e = 0; e < 8; ++e) v[e] = Lt[tg * 32 + u * 8 + e][d];
    *(bf16x8*)(q + u * 8) = v;
  }
}

// ---------------- QKV GEMM: 256x192 tile, BK=64, 8 waves, double-buffered --
// Each wave computes 128x48 (8x3 of 16x16x32). Same swizzle/staging algebra
// as the proven 128^2 kernel; issue-early staging + 1 barrier per K-step.
__global__ __launch_bounds__(512, 2) void gemm_qkv(
    const bf16_t* __restrict__ A, const bf16_t* __restrict__ Bt,
    const float* __restrict__ bias,
    bf16_t* __restrict__ Qb, bf16_t* __restrict__ Kb, bf16_t* __restrict__ Vb) {
  __shared__ bf16_t Als[2][256][64];
  __shared__ bf16_t Bls[2][192][64];
  const int m0 = blockIdx.x * 256;
  const int n0 = blockIdx.y * 192;
  const int tid = threadIdx.x;
  const int lane = tid & 63;
  const int w = tid >> 6;            // 0..7
  const int wr = w >> 2;             // 0..1 : rows wr*128..+127
  const int wc = w & 3;              // 0..3 : cols wc*48..+47
  const int lr = lane & 15, g = lane >> 4;
  const int sw = (lane & 7) << 3;
  const int srow = lane >> 3;
  const int soff = ((lane & 7) ^ srow) * 8;

  f32x4 acc[8][3] = {};

  // prologue: stage tile 0 -> buf 0
#pragma unroll
  for (int c = 0; c < 4; ++c)
    gll16(A + (size_t)(m0 + w * 32 + c * 8 + srow) * 1024 + soff,
          &Als[0][w * 32 + c * 8][0]);
#pragma unroll
  for (int c = 0; c < 3; ++c)
    gll16(Bt + (size_t)(n0 + w * 24 + c * 8 + srow) * 1024 + soff,
          &Bls[0][w * 24 + c * 8][0]);
  __syncthreads();

  for (int kt = 0; kt < 16; ++kt) {
    const int cbuf = kt & 1, nbuf = cbuf ^ 1;
    if (kt + 1 < 16) {
      const int k1 = (kt + 1) * 64;
#pragma unroll
      for (int c = 0; c < 4; ++c)
        gll16(A + (size_t)(m0 + w * 32 + c * 8 + srow) * 1024 + k1 + soff,
              &Als[nbuf][w * 32 + c * 8][0]);
#pragma unroll
      for (int c = 0; c < 3; ++c)
        gll16(Bt + (size_t)(n0 + w * 24 + c * 8 + srow) * 1024 + k1 + soff,
              &Bls[nbuf][w * 24 + c * 8][0]);
    }
#pragma unroll
    for (int ks = 0; ks < 2; ++ks) {
      bf16x8 bfv[3];
#pragma unroll
      for (int j = 0; j < 3; ++j)
        bfv[j] = *(const bf16x8*)&Bls[cbuf][wc * 48 + j * 16 + lr][(ks * 32 + g * 8) ^ sw];
#pragma unroll
      for (int i = 0; i < 8; ++i) {
        bf16x8 af = *(const bf16x8*)&Als[cbuf][wr * 128 + i * 16 + lr][(ks * 32 + g * 8) ^ sw];
#pragma unroll
        for (int j = 0; j < 3; ++j)
          acc[i][j] = __builtin_amdgcn_mfma_f32_16x16x32_bf16(af, bfv[j], acc[i][j], 0, 0, 0);
      }
    }
    __syncthreads();   // next tile staged (vmcnt0) + all reads of cbuf done
  }

  // epilogue: C/D layout col=lane&15, row=(lane>>4)*4+e
#pragma unroll
  for (int i = 0; i < 8; ++i) {
#pragma unroll
    for (int j = 0; j < 3; ++j) {
#pragma unroll
      for (int e = 0; e < 4; ++e) {
        int m = m0 + wr * 128 + i * 16 + g * 4 + e;
        int n = n0 + wc * 48 + j * 16 + lr;
        float v = acc[i][j][e] + bias[n];
        int b = m >> 11, t = m & 2047;
        int which = n >> 10, hn = n & 1023;
        int h = hn >> 6, d = hn & 63;
        if (which == 0) v *= QSCALE;
        bf16_t* dst = (which == 0) ? Qb : (which == 1) ? Kb : Vb;
        dst[(((size_t)(b * 16 + h)) * 2048 + t) * 64 + d] = (bf16_t)v;
      }
    }
  }
}

// ---------------- proj GEMM: 128x128 tile (proven form) --------------------
__global__ __launch_bounds__(256, 3) void gemm_proj(
    const bf16_t* __restrict__ A, const bf16_t* __restrict__ Bt,
    const float* __restrict__ bias, float* __restrict__ Out) {
  __shared__ bf16_t Als[128][64];
  __shared__ bf16_t Bls[128][64];
  const int m0 = blockIdx.x * 128;
  const int n0 = blockIdx.y * 128;
  const int tid = threadIdx.x;
  const int lane = tid & 63;
  const int w = tid >> 6;
  const int wm = w >> 1, wn = w & 1;
  const int lr = lane & 15, g = lane >> 4;
  const int sw = (lane & 7) << 3;
  const int srow = lane >> 3;
  const int soff = ((lane & 7) ^ srow) * 8;

  f32x4 acc[4][4] = {};

  for (int k0 = 0; k0 < 1024; k0 += 64) {
#pragma unroll
    for (int c = 0; c < 4; ++c) {
      int r = w * 32 + c * 8 + srow;
      gll16(A + (size_t)(m0 + r) * 1024 + k0 + soff, &Als[w * 32 + c * 8][0]);
      gll16(Bt + (size_t)(n0 + r) * 1024 + k0 + soff, &Bls[w * 32 + c * 8][0]);
    }
    __syncthreads();
#pragma unroll
    for (int ks = 0; ks < 2; ++ks) {
      bf16x8 af[4], bfv[4];
#pragma unroll
      for (int i = 0; i < 4; ++i)
        af[i] = *(const bf16x8*)&Als[wm * 64 + i * 16 + lr][(ks * 32 + g * 8) ^ sw];
#pragma unroll
      for (int j = 0; j < 4; ++j)
        bfv[j] = *(const bf16x8*)&Bls[wn * 64 + j * 16 + lr][(ks * 32 + g * 8) ^ sw];
#pragma unroll
      for (int i = 0; i < 4; ++i)
#pragma unroll
        for (int j = 0; j < 4; ++j)
          acc[i][j] = __builtin_amdgcn_mfma_f32_16x16x32_bf16(af[i], bfv[j], acc[i][j], 0, 0, 0);
    }
    __syncthreads();
  }

#pragma unroll
  for (int i = 0; i < 4; ++i) {
#pragma unroll
    for (int j = 0; j < 4; ++j) {
#pragma unroll
      for (int e = 0; e < 4; ++e) {
        int m = m0 + wm * 64 + i * 16 + g * 4 + e;
        int n = n0 + wn * 64 + j * 16 + lr;
        Out[(size_t)m * 1024 + n] = acc[i][j][e] + bias[n];
      }
    }
  }
}

// ---------------- flash attention, causal, hd=64, split-K ------------------
// QBLK=128 (4 waves x 32 q-rows), KVBLK=64, 32x32x16 MFMA, P in registers.
// K+Vt TRIPLE-buffered [64][64] (48KB -> 3 blocks/CU), pure-DMA staging,
// prefetch distance 2, counted vmcnt(4) + raw s_barrier.
__global__ __launch_bounds__(256, 3) void attn_fwd(
    const bf16_t* __restrict__ Qb, const bf16_t* __restrict__ Kb,
    const bf16_t* __restrict__ Vtg, bf16_t* __restrict__ Ob,
    bf16_t* __restrict__ Po, float* __restrict__ Pml) {
  __shared__ bf16_t Kls[3][64][64];   // K tile; LDS[r][c*8] = K[r][(c^(r&7))*8]
  __shared__ bf16_t Vt[3][64][64];    // V^T tile; same swizzle on k-chunks

  // 768 blocks = 8 xcd x 4 bh x 24 slots (longest-first)
  int id = blockIdx.x;
  int xcd = id & 7, r = id >> 3;
  int bh = xcd * 4 + (r & 3);
  int j = kOrder[r >> 2];
  int qb, kt0, kt1, part;
  if (j < 8) {
    qb = j; kt0 = 0; kt1 = 2 * qb + 2; part = -1;
  } else {
    qb = 8 + ((j - 8) >> 1);
    part = (j - 8) & 1;
    int nA = qb + 1;
    kt0 = part ? nA : 0;
    kt1 = part ? (2 * qb + 2) : nA;
  }
  int b = bh >> 4, h = bh & 15;

  const int tid = threadIdx.x, lane = tid & 63, w = tid >> 6;
  const int q32 = lane & 31;
  const int hi = lane >> 5;
  const int ksw = (q32 & 7) << 3;     // read key for both K and V^T tiles
  const bf16_t* Qp = Qb + (size_t)bh * 2048 * 64;
  const bf16_t* Kp = Kb + (size_t)bh * 2048 * 64;
  const bf16_t* Vtp = Vtg + (size_t)bh * 131072;   // [64][2048]

  const int q0 = qb * 128;
  const int qrow = q0 + w * 32 + q32;

  const int sr = lane >> 3;                 // row within call
  const int sc = ((lane & 7) ^ sr) * 8;     // source chunk (elements)
  int vdo[2];
#pragma unroll
  for (int c = 0; c < 2; ++c)
    vdo[c] = (w * 16 + c * 8 + sr) * 2048 + sc;

  bf16x8 qf[4];
#pragma unroll
  for (int ds = 0; ds < 4; ++ds)
    qf[ds] = *(const bf16x8*)(Qp + (size_t)qrow * 64 + ds * 16 + hi * 8);

  float m_run = -3e38f, l_run = 0.f;
  f32x16 o_acc[2] = {};

  // ---- prologue: stage tiles kt0 -> buf0, kt0+1 -> buf1 (pure DMA) ----
  {
    const int kp = kt0 * 64;
#pragma unroll
    for (int c = 0; c < 2; ++c) {
      int rb = w * 16 + c * 8;
      gll16(Kp + (size_t)(kp + rb + sr) * 64 + sc, &Kls[0][rb][0]);
      gll16(Vtp + vdo[c] + kp, &Vt[0][rb][0]);
    }
    const int kp1 = kp + 64;   // kt0+1 < kt1 always (min job len 2)
#pragma unroll
    for (int c = 0; c < 2; ++c) {
      int rb = w * 16 + c * 8;
      gll16(Kp + (size_t)(kp1 + rb + sr) * 64 + sc, &Kls[1][rb][0]);
      gll16(Vtp + vdo[c] + kp1, &Vt[1][rb][0]);
    }
    asm volatile("s_waitcnt vmcnt(4)" ::: "memory");  // buf0 (+Q) complete
    __builtin_amdgcn_s_barrier();
  }

  int cb = 0;
  for (int kt = kt0; kt < kt1; ++kt) {
    const bool pf2 = (kt + 2 < kt1);
    const int pf = (cb >= 1) ? cb - 1 : 2;   // (cb+2)%3

    // ---- issue tile kt+2's DMA (stays in flight across the barrier) ----
    if (pf2) {
      const int kn = (kt + 2) * 64;
#pragma unroll
      for (int c = 0; c < 2; ++c) {
        int rb = w * 16 + c * 8;
        gll16(Kp + (size_t)(kn + rb + sr) * 64 + sc, &Kls[pf][rb][0]);
        gll16(Vtp + vdo[c] + kn, &Vt[pf][rb][0]);
      }
    }

    // ---- causal decode: rel 0/1 are diagonal 64-tiles ----
    const int rel = kt - 2 * qb;
    int nfa = 2, dfa = -1;
    if (rel == 0) {
      if (w == 0) { nfa = 1; dfa = 0; }
      else if (w == 1) { dfa = 1; }
    } else if (rel == 1) {
      if (w < 2) nfa = 0;
      else if (w == 2) { nfa = 1; dfa = 0; }
      else { dfa = 1; }
    }

    if (nfa > 0) {
      f32x16 s[2] = {};
      __builtin_amdgcn_s_setprio(1);
#pragma unroll
      for (int fa = 0; fa < 2; ++fa) {
        if (fa < nfa) {
#pragma unroll
          for (int ds = 0; ds < 4; ++ds) {
            bf16x8 kf = *(const bf16x8*)&Kls[cb][fa * 32 + q32][(ds * 16 + hi * 8) ^ ksw];
            s[fa] = __builtin_amdgcn_mfma_f32_32x32x16_bf16(kf, qf[ds], s[fa], 0, 0, 0);
          }
        }
      }
      __builtin_amdgcn_s_setprio(0);

      float mloc = -3e38f;
#pragma unroll
      for (int fa = 0; fa < 2; ++fa) {
        if (fa < nfa) {
          if (fa == dfa) {
#pragma unroll
            for (int rr = 0; rr < 16; ++rr) {
              int km = (rr & 3) + 8 * (rr >> 2) + 4 * hi;
              if (km > q32) s[fa][rr] = -3e38f;
            }
          }
#pragma unroll
          for (int rr = 0; rr < 16; rr += 2)
            mloc = fmaxf(mloc, fmaxf(s[fa][rr], s[fa][rr + 1]));
        }
      }
      mloc = fmaxf(mloc, __shfl_xor(mloc, 32, 64));
      if (!__all(mloc <= m_run + 8.0f)) {  // defer-max (T13)
        float mnew = fmaxf(m_run, mloc);
        float rs = __builtin_amdgcn_exp2f(m_run - mnew);
        m_run = mnew;
        l_run *= rs;
        o_acc[0] *= rs;
        o_acc[1] *= rs;
      }

      float lsum = 0.f;
#pragma unroll
      for (int fa = 0; fa < 2; ++fa) {
        if (fa < nfa) {
          float p[16];
#pragma unroll
          for (int rr = 0; rr < 16; ++rr) {
            p[rr] = __builtin_amdgcn_exp2f(s[fa][rr] - m_run);
            lsum += p[rr];
          }
          u32 x0 = pack2(p[0], p[1]),   x1 = pack2(p[2], p[3]);
          u32 x2 = pack2(p[4], p[5]),   x3 = pack2(p[6], p[7]);
          u32 y0 = pack2(p[8], p[9]),   y1 = pack2(p[10], p[11]);
          u32 y2 = pack2(p[12], p[13]), y3 = pack2(p[14], p[15]);
          u32 z0 = hi ? x0 : x2;
          u32 z1 = hi ? x1 : x3;
          u32 z2 = hi ? y0 : y2;
          u32 z3 = hi ? y1 : y3;
          z0 = (u32)__shfl_xor((int)z0, 32, 64);
          z1 = (u32)__shfl_xor((int)z1, 32, 64);
          z2 = (u32)__shfl_xor((int)z2, 32, 64);
          z3 = (u32)__shfl_xor((int)z3, 32, 64);
          u32x4 pw0 = hi ? (u32x4){z0, z1, x2, x3} : (u32x4){x0, x1, z0, z1};
          u32x4 pw1 = hi ? (u32x4){z2, z3, y2, y3} : (u32x4){y0, y1, z2, z3};
          bf16x8 P0 = __builtin_bit_cast(bf16x8, pw0);
          bf16x8 P1 = __builtin_bit_cast(bf16x8, pw1);
          __builtin_amdgcn_s_setprio(1);
#pragma unroll
          for (int db = 0; db < 2; ++db) {
            int d = db * 32 + q32;
            bf16x8 vf0 = *(const bf16x8*)&Vt[cb][d][(fa * 32 + hi * 8) ^ ksw];
            o_acc[db] = __builtin_amdgcn_mfma_f32_32x32x16_bf16(vf0, P0, o_acc[db], 0, 0, 0);
            bf16x8 vf1 = *(const bf16x8*)&Vt[cb][d][(fa * 32 + 16 + hi * 8) ^ ksw];
            o_acc[db] = __builtin_amdgcn_mfma_f32_32x32x16_bf16(vf1, P1, o_acc[db], 0, 0, 0);
          }
          __builtin_amdgcn_s_setprio(0);
        }
      }
      lsum += __shfl_xor(lsum, 32, 64);
      l_run += lsum;
    }

    if (pf2) {
      asm volatile("s_waitcnt vmcnt(4)" ::: "memory");
    } else {
      asm volatile("s_waitcnt vmcnt(0)" ::: "memory");
    }
    __builtin_amdgcn_s_barrier();
    cb = (cb == 2) ? 0 : cb + 1;
  }  // kt

  const int prow = w * 32 + q32;
  if (part < 0) {
    float inv = 1.0f / l_run;
    bf16_t* obase = Ob + ((size_t)(b * 2048 + qrow)) * 1024 + h * 64;
#pragma unroll
    for (int db = 0; db < 2; ++db) {
#pragma unroll
      for (int rg = 0; rg < 4; ++rg) {
        bf16x4 ov = {(bf16_t)(o_acc[db][rg * 4 + 0] * inv),
                     (bf16_t)(o_acc[db][rg * 4 + 1] * inv),
                     (bf16_t)(o_acc[db][rg * 4 + 2] * inv),
                     (bf16_t)(o_acc[db][rg * 4 + 3] * inv)};
        *(bf16x4*)(obase + db * 32 + rg * 8 + hi * 4) = ov;
      }
    }
  } else {
    int sidx = bh * 16 + (qb - 8) * 2 + part;
    bf16_t* po = (part == 0)
        ? Ob + ((size_t)(b * 2048 + qrow)) * 1024 + h * 64
        : Po + (size_t)(bh * 8 + (qb - 8)) * 8192 + prow * 64;
#pragma unroll
    for (int db = 0; db < 2; ++db) {
#pragma unroll
      for (int rg = 0; rg < 4; ++rg) {
        bf16x4 ov = {(bf16_t)o_acc[db][rg * 4 + 0], (bf16_t)o_acc[db][rg * 4 + 1],
                     (bf16_t)o_acc[db][rg * 4 + 2], (bf16_t)o_acc[db][rg * 4 + 3]};
        *(bf16x4*)(po + db * 32 + rg * 8 + hi * 4) = ov;
      }
    }
    if (hi == 0) {
      Pml[sidx * 256 + prow * 2] = m_run;
      Pml[sidx * 256 + prow * 2 + 1] = l_run;
    }
  }
}

// ---------------- merge split-K partials (Ob-part0 + Po-part1) -------------
__global__ __launch_bounds__(256) void attn_merge(
    const bf16_t* __restrict__ Po, const float* __restrict__ Pml,
    bf16_t* __restrict__ Ob) {
  int blk = blockIdx.x;           // 0..255 = bh(32) x qb8(8)
  int bh = blk >> 3, qb8 = blk & 7;
  int qb = 8 + qb8;
  int b = bh >> 4, h = bh & 15;
  int sA = bh * 16 + qb8 * 2, sB = sA + 1;
  int t = threadIdx.x;
  int row = t >> 1, c0 = (t & 1) * 32;

  float mA = Pml[sA * 256 + row * 2], lA = Pml[sA * 256 + row * 2 + 1];
  float mB = Pml[sB * 256 + row * 2], lB = Pml[sB * 256 + row * 2 + 1];
  float m = fmaxf(mA, mB);
  float wA = __builtin_amdgcn_exp2f(mA - m);
  float wB = __builtin_amdgcn_exp2f(mB - m);
  float inv = 1.0f / (lA * wA + lB * wB);
  wA *= inv;
  wB *= inv;

  bf16_t* ob = Ob + ((size_t)(b * 2048 + qb * 128 + row)) * 1024 + h * 64 + c0;
  const bf16_t* pb = Po + (size_t)(bh * 8 + qb8) * 8192 + row * 64 + c0;
#pragma unroll
  for (int u = 0; u < 4; ++u) {
    bf16x8 a = *(const bf16x8*)(ob + u * 8);
    bf16x8 c = *(const bf16x8*)(pb + u * 8);
    bf16x8 o;
#pragma unroll
    for (int i = 0; i < 8; ++i)
      o[i] = (bf16_t)((float)a[i] * wA + (float)c[i] * wB);
    *(bf16x8*)(ob + u * 8) = o;
  }
}

// ---------------------------------------------------------------------------
extern "C" void kernel_launch(void* const* d_in, const int* in_sizes, int n_in,
                              void* d_out, int out_size, void* d_ws, size_t ws_size,
                              hipStream_t stream) {
  const float* x      = (const float*)d_in[0];
  const float* W_attn = (const float*)d_in[1];
  const float* b_attn = (const float*)d_in[2];
  const float* A_attn = (const float*)d_in[3];
  const float* B_attn = (const float*)d_in[4];
  const float* W_proj = (const float*)d_in[5];
  const float* b_proj = (const float*)d_in[6];
  const float* A_proj = (const float*)d_in[7];
  const float* B_proj = (const float*)d_in[8];
  float* out = (float*)d_out;

  char* ws = (char*)d_ws;
  bf16_t* WaE = (bf16_t*)(ws);               // dead after QKV gemm
  bf16_t* WpE = (bf16_t*)(ws + 6291456);     // live until proj
  bf16_t* Xb  = (bf16_t*)(ws + 8388608);     // dead after QKV gemm
  bf16_t* Qb  = (bf16_t*)(ws + 16777216);    // [B*H][T][64]
  bf16_t* Kb  = (bf16_t*)(ws + 25165824);
  bf16_t* Vb  = (bf16_t*)(ws + 33554432);
  bf16_t* Ob  = (bf16_t*)(ws + 41943040);    // [B*T][C] bf16
  // reuse of dead regions during attention:
  bf16_t* Vtg = (bf16_t*)(ws + 8388608);     // V^T [bh][64][2048] (in Xb)
  bf16_t* Po  = (bf16_t*)(ws);               // 4MB (in WaE)
  float*  Pml = (float*)(ws + 4194304);      // 512KB (in WaE)

  prep_all<<<20480, 256, 0, stream>>>(W_attn, B_attn, A_attn, W_proj, B_proj, A_proj,
                                      (const float4*)x, WaE, WpE, (bf16x4*)Xb);

  gemm_qkv<<<dim3(16, 16), 512, 0, stream>>>(Xb, WaE, b_attn, Qb, Kb, Vb);
  transpose_v<<<512, 256, 0, stream>>>(Vb, Vtg);
  attn_fwd<<<768, 256, 0, stream>>>(Qb, Kb, Vtg, Ob, Po, Pml);
  attn_merge<<<256, 256, 0, stream>>>(Po, Pml, Ob);
  gemm_proj<<<dim3(32, 8), 256, 0, stream>>>(Ob, WpE, b_proj, out);
}